// Round 1
// baseline (483.888 us; speedup 1.0000x reference)
//
#include <hip/hip_runtime.h>
#include <hip/hip_bf16.h>

#define NUM_HEADS 16
#define HEAD_DIM  64
#define HIDDEN    1024
#define BATCH     2
#define SEQ       2048
#define K_DIM     HIDDEN
#define INV_NORM  0.125f

typedef __attribute__((ext_vector_type(4))) float f32x4;
typedef __attribute__((ext_vector_type(8))) short bf16x8;
typedef unsigned short u16;

__device__ inline u16 f2bf(float f) {
    __hip_bfloat16 h = __float2bfloat16(f);
    return __builtin_bit_cast(u16, h);
}

__device__ inline f32x4 mfma16(bf16x8 a, bf16x8 b, f32x4 c) {
    return __builtin_amdgcn_mfma_f32_16x16x32_bf16(a, b, c, 0, 0, 0);
}

// ---------------- fp32 -> bf16 conversion ----------------
__global__ void cvt_f32_bf16(const float* __restrict__ in, u16* __restrict__ out, int n) {
    int i = (blockIdx.x * blockDim.x + threadIdx.x) * 4;
    if (i >= n) return;
    const float4 v = *reinterpret_cast<const float4*>(in + i);
    ushort4 o;
    o.x = f2bf(v.x); o.y = f2bf(v.y); o.z = f2bf(v.z); o.w = f2bf(v.w);
    *reinterpret_cast<ushort4*>(out + i) = o;
}

// ---------------- QKV GEMM: fused = x @ Wqkv^T + b, scatter to q/k/vT ----------------
// A: [4096][1024] bf16 (x), W: [3072][1024] bf16. Both K-major -> direct MFMA frags.
__global__ __launch_bounds__(256) void gemm_qkv(
        const u16* __restrict__ A, const u16* __restrict__ W,
        const float* __restrict__ bias,
        u16* __restrict__ qo, u16* __restrict__ ko, u16* __restrict__ vTo) {
    const int wave = threadIdx.x >> 6;
    const int lane = threadIdx.x & 63;
    const int g = lane >> 4, ln = lane & 15;
    const int m0 = blockIdx.x * 64 + (wave >> 1) * 32;
    const int n0 = blockIdx.y * 64 + (wave & 1) * 32;
    const u16* a0p = A + (size_t)(m0 + ln) * K_DIM + g * 8;
    const u16* a1p = a0p + 16 * K_DIM;
    const u16* b0p = W + (size_t)(n0 + ln) * K_DIM + g * 8;
    const u16* b1p = b0p + 16 * K_DIM;
    f32x4 acc[2][2] = {};
    for (int k0 = 0; k0 < K_DIM; k0 += 32) {
        bf16x8 a0 = *reinterpret_cast<const bf16x8*>(a0p + k0);
        bf16x8 a1 = *reinterpret_cast<const bf16x8*>(a1p + k0);
        bf16x8 b0 = *reinterpret_cast<const bf16x8*>(b0p + k0);
        bf16x8 b1 = *reinterpret_cast<const bf16x8*>(b1p + k0);
        acc[0][0] = mfma16(a0, b0, acc[0][0]);
        acc[0][1] = mfma16(a0, b1, acc[0][1]);
        acc[1][0] = mfma16(a1, b0, acc[1][0]);
        acc[1][1] = mfma16(a1, b1, acc[1][1]);
    }
    for (int mi = 0; mi < 2; ++mi)
    for (int ni = 0; ni < 2; ++ni) {
        int c = n0 + ni * 16 + ln;          // fused column: h*192 + which*64 + d
        int h = c / 192, rem = c % 192;
        int which = rem / 64, d = rem % 64; // uniform 'which'/'h' within a 16-col frag
        float bv = bias[c];
        for (int r = 0; r < 4; ++r) {
            int m = m0 + mi * 16 + g * 4 + r;
            int bb = m >> 11, s = m & (SEQ - 1);
            int bh = bb * NUM_HEADS + h;
            u16 o = f2bf(acc[mi][ni][r] + bv);
            if (which == 0)      qo[((size_t)bh * SEQ + s) * HEAD_DIM + d] = o;
            else if (which == 1) ko[((size_t)bh * SEQ + s) * HEAD_DIM + d] = o;
            else                 vTo[((size_t)bh * HEAD_DIM + d) * SEQ + s] = o;
        }
    }
}

// ---------------- Flash attention: 1 wave = 16 q-rows, key tiles of 32 ----------------
__global__ __launch_bounds__(256) void attn(
        const u16* __restrict__ Q, const u16* __restrict__ Kb,
        const u16* __restrict__ VT, const float* __restrict__ alibi,
        u16* __restrict__ ctx) {
    __shared__ __align__(16) u16 plds[4][16][40];  // per-wave P transpose tile, padded
    const int wave = threadIdx.x >> 6;
    const int lane = threadIdx.x & 63;
    const int g = lane >> 4, ln = lane & 15;
    const int bh = blockIdx.y;
    const int qr0 = blockIdx.x * 64 + wave * 16;
    const size_t qkbase = (size_t)bh * SEQ;

    bf16x8 qf[2];
    qf[0] = *reinterpret_cast<const bf16x8*>(Q + (qkbase + qr0 + ln) * HEAD_DIM + g * 8);
    qf[1] = *reinterpret_cast<const bf16x8*>(Q + (qkbase + qr0 + ln) * HEAD_DIM + 32 + g * 8);

    f32x4 o[4] = {};
    float m_i[4], l_i[4];
    for (int r = 0; r < 4; ++r) { m_i[r] = -INFINITY; l_i[r] = 0.f; }
    const float* al = alibi + (size_t)bh * SEQ;

    const int ntiles = (qr0 + 47) / 32;  // keys < qr0+16
    for (int t = 0; t < ntiles; ++t) {
        const int k0 = t * 32;
        f32x4 sc[2] = {};
        for (int nk = 0; nk < 2; ++nk) {
            const u16* kp = Kb + (qkbase + k0 + nk * 16 + ln) * HEAD_DIM + g * 8;
            bf16x8 kf0 = *reinterpret_cast<const bf16x8*>(kp);
            bf16x8 kf1 = *reinterpret_cast<const bf16x8*>(kp + 32);
            sc[nk] = mfma16(qf[0], kf0, sc[nk]);
            sc[nk] = mfma16(qf[1], kf1, sc[nk]);
        }
        float a0 = al[k0 + ln], a1 = al[k0 + 16 + ln];
        for (int r = 0; r < 4; ++r) {
            int row = qr0 + g * 4 + r;
            float s0 = sc[0][r] * INV_NORM + a0;
            float s1 = sc[1][r] * INV_NORM + a1;
            if (k0 + ln > row)      s0 = -INFINITY;   // causal: col > row masked
            if (k0 + 16 + ln > row) s1 = -INFINITY;
            float mx = fmaxf(s0, s1);
            for (int off = 8; off; off >>= 1) mx = fmaxf(mx, __shfl_xor(mx, off));
            float mnew = fmaxf(m_i[r], mx);           // always finite (key<=row exists)
            float scl = __expf(m_i[r] - mnew);
            float p0 = __expf(s0 - mnew);
            float p1 = __expf(s1 - mnew);
            float rs = p0 + p1;
            for (int off = 8; off; off >>= 1) rs += __shfl_xor(rs, off);
            l_i[r] = l_i[r] * scl + rs;
            m_i[r] = mnew;
            o[0][r] *= scl; o[1][r] *= scl; o[2][r] *= scl; o[3][r] *= scl;
            plds[wave][g * 4 + r][ln] = f2bf(p0);
            plds[wave][g * 4 + r][16 + ln] = f2bf(p1);
        }
        asm volatile("s_waitcnt lgkmcnt(0)" ::: "memory");  // wave-internal LDS transpose
        bf16x8 pa = *reinterpret_cast<const bf16x8*>(&plds[wave][ln][g * 8]);
        const u16* vp = VT + ((size_t)bh * HEAD_DIM + ln) * SEQ + k0 + g * 8;
        for (int nd = 0; nd < 4; ++nd) {
            bf16x8 vf = *reinterpret_cast<const bf16x8*>(vp + (size_t)nd * 16 * SEQ);
            o[nd] = mfma16(pa, vf, o[nd]);
        }
    }
    const int b = bh >> 4, h = bh & 15;
    for (int nd = 0; nd < 4; ++nd)
        for (int r = 0; r < 4; ++r) {
            int row = qr0 + g * 4 + r;
            float v = o[nd][r] / l_i[r];
            ctx[((size_t)(b * SEQ + row)) * HIDDEN + h * HEAD_DIM + nd * 16 + ln] = f2bf(v);
        }
}

// ---------------- Dense GEMM + bias + residual ----------------
__global__ __launch_bounds__(256) void gemm_dense(
        const u16* __restrict__ A, const u16* __restrict__ W,
        const float* __restrict__ bias, const float* __restrict__ residual,
        float* __restrict__ out) {
    const int wave = threadIdx.x >> 6;
    const int lane = threadIdx.x & 63;
    const int g = lane >> 4, ln = lane & 15;
    const int m0 = blockIdx.x * 64 + (wave >> 1) * 32;
    const int n0 = blockIdx.y * 64 + (wave & 1) * 32;
    const u16* a0p = A + (size_t)(m0 + ln) * K_DIM + g * 8;
    const u16* a1p = a0p + 16 * K_DIM;
    const u16* b0p = W + (size_t)(n0 + ln) * K_DIM + g * 8;
    const u16* b1p = b0p + 16 * K_DIM;
    f32x4 acc[2][2] = {};
    for (int k0 = 0; k0 < K_DIM; k0 += 32) {
        bf16x8 a0 = *reinterpret_cast<const bf16x8*>(a0p + k0);
        bf16x8 a1 = *reinterpret_cast<const bf16x8*>(a1p + k0);
        bf16x8 b0 = *reinterpret_cast<const bf16x8*>(b0p + k0);
        bf16x8 b1 = *reinterpret_cast<const bf16x8*>(b1p + k0);
        acc[0][0] = mfma16(a0, b0, acc[0][0]);
        acc[0][1] = mfma16(a0, b1, acc[0][1]);
        acc[1][0] = mfma16(a1, b0, acc[1][0]);
        acc[1][1] = mfma16(a1, b1, acc[1][1]);
    }
    for (int mi = 0; mi < 2; ++mi)
    for (int ni = 0; ni < 2; ++ni) {
        int c = n0 + ni * 16 + ln;
        float bv = bias[c];
        for (int r = 0; r < 4; ++r) {
            int m = m0 + mi * 16 + g * 4 + r;
            out[(size_t)m * HIDDEN + c] = acc[mi][ni][r] + bv + residual[(size_t)m * HIDDEN + c];
        }
    }
}

extern "C" void kernel_launch(void* const* d_in, const int* in_sizes, int n_in,
                              void* d_out, int out_size, void* d_ws, size_t ws_size,
                              hipStream_t stream) {
    const float* x        = (const float*)d_in[0];  // [1,B,S,H]
    const float* residual = (const float*)d_in[1];  // [B,S,H]
    const float* alibi    = (const float*)d_in[2];  // [B*H,1,S]
    const float* W_qkv    = (const float*)d_in[4];  // [3H,H]
    const float* b_qkv    = (const float*)d_in[5];
    const float* W_dense  = (const float*)d_in[6];  // [H,H]
    const float* b_dense  = (const float*)d_in[7];
    float* out = (float*)d_out;

    char* ws = (char*)d_ws;
    u16* xb  = (u16*)(ws);                 //  8 MB  x bf16
    u16* wqb = (u16*)(ws + 8388608);       //  6 MB  W_qkv bf16
    u16* wdb = (u16*)(ws + 14680064);      //  2 MB  W_dense bf16
    u16* q   = (u16*)(ws + 16777216);      //  8 MB  [B][H][S][64]
    u16* k   = (u16*)(ws + 25165824);      //  8 MB  [B][H][S][64]
    u16* vT  = (u16*)(ws + 33554432);      //  8 MB  [B][H][64][S]
    u16* ctx = (u16*)(ws + 41943040);      //  8 MB  [B*S][1024]

    cvt_f32_bf16<<<4096, 256, 0, stream>>>(x, xb, 4194304);
    cvt_f32_bf16<<<3072, 256, 0, stream>>>(W_qkv, wqb, 3145728);
    cvt_f32_bf16<<<1024, 256, 0, stream>>>(W_dense, wdb, 1048576);
    gemm_qkv<<<dim3(64, 48), 256, 0, stream>>>(xb, wqb, b_qkv, q, k, vT);
    attn<<<dim3(32, 32), 256, 0, stream>>>(q, k, vT, alibi, ctx);
    gemm_dense<<<dim3(64, 16), 256, 0, stream>>>(ctx, wdb, b_dense, residual, out);
}

// Round 2
// 271.978 us; speedup vs baseline: 1.7791x; 1.7791x over previous
//
#include <hip/hip_runtime.h>
#include <hip/hip_bf16.h>

#define NUM_HEADS 16
#define HEAD_DIM  64
#define HIDDEN    1024
#define BATCH     2
#define SEQ       2048
#define K_DIM     HIDDEN
#define INV_NORM  0.125f

typedef __attribute__((ext_vector_type(4)))  float f32x4;
typedef __attribute__((ext_vector_type(16))) float f32x16;
typedef __attribute__((ext_vector_type(8)))  short bf16x8;
typedef __attribute__((ext_vector_type(4)))  unsigned int u32x4;
typedef unsigned short u16;

__device__ inline u16 f2bf(float f) {
    __hip_bfloat16 h = __float2bfloat16(f);
    return __builtin_bit_cast(u16, h);
}

__device__ inline f32x16 mfma32(bf16x8 a, bf16x8 b, f32x16 c) {
    return __builtin_amdgcn_mfma_f32_32x32x16_bf16(a, b, c, 0, 0, 0);
}

// ---------------- fp32 -> bf16 conversion ----------------
__global__ void cvt_f32_bf16(const float* __restrict__ in, u16* __restrict__ out, int n) {
    int i = (blockIdx.x * blockDim.x + threadIdx.x) * 4;
    if (i >= n) return;
    const float4 v = *reinterpret_cast<const float4*>(in + i);
    ushort4 o;
    o.x = f2bf(v.x); o.y = f2bf(v.y); o.z = f2bf(v.z); o.w = f2bf(v.w);
    *reinterpret_cast<ushort4*>(out + i) = o;
}

// ---------------- QKV GEMM: 128x128 block, 64x64/wave, 32x32x16 MFMA ----------------
// A:[4096][1024], W:[3072][1024] bf16, both K-major -> direct frags.
__global__ __launch_bounds__(256) void gemm_qkv(
        const u16* __restrict__ A, const u16* __restrict__ W,
        const float* __restrict__ bias,
        u16* __restrict__ qo, u16* __restrict__ ko, u16* __restrict__ vTo) {
    // XCD swizzle: 768 blocks, 96/XCD chunk -> each XCD holds 3 B-panels in L2
    int lin = blockIdx.x;
    int sw = (lin & 7) * 96 + (lin >> 3);
    int bx = sw & 31;   // 32 m-blocks
    int by = sw >> 5;   // 24 n-blocks
    const int wave = threadIdx.x >> 6;
    const int lane = threadIdx.x & 63;
    const int la = lane & 31, hi = lane >> 5;
    const int m0 = bx * 128 + (wave >> 1) * 64;
    const int n0 = by * 128 + (wave & 1) * 64;
    const u16* ap = A + (size_t)(m0 + la) * K_DIM + hi * 8;
    const u16* bp = W + (size_t)(n0 + la) * K_DIM + hi * 8;
    f32x16 acc[2][2] = {};
    for (int k0 = 0; k0 < K_DIM; k0 += 16) {
        bf16x8 a0 = *reinterpret_cast<const bf16x8*>(ap + k0);
        bf16x8 a1 = *reinterpret_cast<const bf16x8*>(ap + 32 * K_DIM + k0);
        bf16x8 b0 = *reinterpret_cast<const bf16x8*>(bp + k0);
        bf16x8 b1 = *reinterpret_cast<const bf16x8*>(bp + 32 * K_DIM + k0);
        acc[0][0] = mfma32(a0, b0, acc[0][0]);
        acc[0][1] = mfma32(a0, b1, acc[0][1]);
        acc[1][0] = mfma32(a1, b0, acc[1][0]);
        acc[1][1] = mfma32(a1, b1, acc[1][1]);
    }
    #pragma unroll
    for (int mi = 0; mi < 2; ++mi)
    #pragma unroll
    for (int ni = 0; ni < 2; ++ni) {
        int c = n0 + ni * 32 + la;          // fused col: h*192 + which*64 + d
        int h = c / 192, rem = c - h * 192;
        int which = rem >> 6, d = rem & 63;
        float bv = bias[c];
        #pragma unroll
        for (int r = 0; r < 16; ++r) {
            int m = m0 + mi * 32 + (r & 3) + 8 * (r >> 2) + 4 * hi;
            int bb = m >> 11, s = m & (SEQ - 1);
            int bh = bb * NUM_HEADS + h;
            u16 o = f2bf(acc[mi][ni][r] + bv);
            if (which == 0)      qo[((size_t)bh * SEQ + s) * HEAD_DIM + d] = o;
            else if (which == 1) ko[((size_t)bh * SEQ + s) * HEAD_DIM + d] = o;
            else                 vTo[((size_t)bh * HEAD_DIM + d) * SEQ + s] = o;
        }
    }
}

// ---------------- Flash attention, swapped operands, no LDS ----------------
// Wave = 32 q-rows; 32-key tiles. QK^T: D[k][q]=mfma(K,Q); PV: D[d][q]=mfma(VT,P).
__global__ __launch_bounds__(256) void attn(
        const u16* __restrict__ Q, const u16* __restrict__ Kb,
        const u16* __restrict__ VT, const float* __restrict__ alibi,
        u16* __restrict__ ctx) {
    // 512 blocks: XCD swizzle (4 heads/XCD -> 2MB K/V in L2), heavy-q first
    int lin = blockIdx.x;
    int sw = (lin & 7) * 64 + (lin >> 3);
    int bh = sw >> 4;
    int xr = 15 - (sw & 15);
    const int wave = threadIdx.x >> 6;
    const int lane = threadIdx.x & 63;
    const int la = lane & 31, hi = lane >> 5;
    const int qw = xr * 128 + wave * 32;
    const size_t sb = (size_t)bh * SEQ;

    const float slope = alibi[sb + 1];   // alibi[bh][s] = slope*s exactly

    const u16* qp = Q + (sb + qw + la) * HEAD_DIM + hi * 8;
    bf16x8 qf0 = *reinterpret_cast<const bf16x8*>(qp);
    bf16x8 qf1 = *reinterpret_cast<const bf16x8*>(qp + 16);
    bf16x8 qf2 = *reinterpret_cast<const bf16x8*>(qp + 32);
    bf16x8 qf3 = *reinterpret_cast<const bf16x8*>(qp + 48);

    float skr[16];
    #pragma unroll
    for (int r = 0; r < 16; ++r)
        skr[r] = slope * (float)((r & 3) + 8 * (r >> 2) + 4 * hi);

    f32x16 o0 = {}, o1 = {};
    float m_i = -INFINITY, l_i = 0.f;

    const int ndiag = qw >> 5;
    for (int t = 0; t <= ndiag; ++t) {
        const int k0 = t * 32;
        const u16* kp = Kb + (sb + k0 + la) * HEAD_DIM + hi * 8;
        bf16x8 kf0 = *reinterpret_cast<const bf16x8*>(kp);
        bf16x8 kf1 = *reinterpret_cast<const bf16x8*>(kp + 16);
        bf16x8 kf2 = *reinterpret_cast<const bf16x8*>(kp + 32);
        bf16x8 kf3 = *reinterpret_cast<const bf16x8*>(kp + 48);
        f32x16 sc = {};
        sc = mfma32(kf0, qf0, sc);
        sc = mfma32(kf1, qf1, sc);
        sc = mfma32(kf2, qf2, sc);
        sc = mfma32(kf3, qf3, sc);

        float s[16];
        const float bsv = slope * (float)k0;
        #pragma unroll
        for (int r = 0; r < 16; ++r)
            s[r] = fmaf(sc[r], INV_NORM, bsv + skr[r]);
        if (t == ndiag) {
            #pragma unroll
            for (int r = 0; r < 16; ++r) {
                int kr = (r & 3) + 8 * (r >> 2) + 4 * hi;
                if (kr > la) s[r] = -INFINITY;   // causal diagonal tile
            }
        }
        // row max: in-register tree + one cross-half exchange
        float ma = fmaxf(fmaxf(s[0], s[1]), fmaxf(s[2], s[3]));
        float mb = fmaxf(fmaxf(s[4], s[5]), fmaxf(s[6], s[7]));
        float mc = fmaxf(fmaxf(s[8], s[9]), fmaxf(s[10], s[11]));
        float md = fmaxf(fmaxf(s[12], s[13]), fmaxf(s[14], s[15]));
        float mx = fmaxf(fmaxf(ma, mb), fmaxf(mc, md));
        mx = fmaxf(mx, __shfl_xor(mx, 32));
        // defer-max (T13): only rescale when max grew by > 8
        if (!__all(mx <= m_i + 8.f)) {
            float mnew = fmaxf(m_i, mx);
            float scl = __expf(m_i - mnew);
            l_i *= scl;
            #pragma unroll
            for (int r = 0; r < 16; ++r) { o0[r] *= scl; o1[r] *= scl; }
            m_i = mnew;
        }
        #pragma unroll
        for (int r = 0; r < 16; ++r) s[r] = __expf(s[r] - m_i);
        float sa = (s[0] + s[1]) + (s[2] + s[3]);
        float sbs = (s[4] + s[5]) + (s[6] + s[7]);
        float scs = (s[8] + s[9]) + (s[10] + s[11]);
        float sd = (s[12] + s[13]) + (s[14] + s[15]);
        float rs = (sa + sbs) + (scs + sd);
        rs += __shfl_xor(rs, 32);
        l_i += rs;

        // pack P quads to bf16 pairs; k of quad m = 8m + 4*hi + {0..3}
        unsigned int pk[8], swp[8];
        #pragma unroll
        for (int m = 0; m < 4; ++m) {
            pk[2 * m]     = (unsigned)f2bf(s[4 * m])     | ((unsigned)f2bf(s[4 * m + 1]) << 16);
            pk[2 * m + 1] = (unsigned)f2bf(s[4 * m + 2]) | ((unsigned)f2bf(s[4 * m + 3]) << 16);
        }
        #pragma unroll
        for (int i = 0; i < 8; ++i) swp[i] = __shfl_xor(pk[i], 32);
        // B-frag kc covers keys kc*16 + 8*hi + j  (octet o = 2*kc + hi)
        u32x4 pb0, pb1;
        pb0[0] = hi ? swp[2] : pk[0];  pb0[1] = hi ? swp[3] : pk[1];
        pb0[2] = hi ? pk[2]  : swp[0]; pb0[3] = hi ? pk[3]  : swp[1];
        pb1[0] = hi ? swp[6] : pk[4];  pb1[1] = hi ? swp[7] : pk[5];
        pb1[2] = hi ? pk[6]  : swp[4]; pb1[3] = hi ? pk[7]  : swp[5];
        bf16x8 pf0 = __builtin_bit_cast(bf16x8, pb0);
        bf16x8 pf1 = __builtin_bit_cast(bf16x8, pb1);

        const u16* vp = VT + ((size_t)bh * HEAD_DIM + la) * SEQ + k0 + hi * 8;
        bf16x8 v00 = *reinterpret_cast<const bf16x8*>(vp);
        bf16x8 v01 = *reinterpret_cast<const bf16x8*>(vp + 16);
        bf16x8 v10 = *reinterpret_cast<const bf16x8*>(vp + 32 * SEQ);
        bf16x8 v11 = *reinterpret_cast<const bf16x8*>(vp + 32 * SEQ + 16);
        o0 = mfma32(v00, pf0, o0);
        o0 = mfma32(v01, pf1, o0);
        o1 = mfma32(v10, pf0, o1);
        o1 = mfma32(v11, pf1, o1);
    }

    const float inv_l = 1.0f / l_i;
    const int b = bh >> 4, h = bh & 15;
    u16* cp = ctx + ((size_t)(b * SEQ + qw + la)) * HIDDEN + h * HEAD_DIM;
    #pragma unroll
    for (int r = 0; r < 16; ++r) {
        int d = (r & 3) + 8 * (r >> 2) + 4 * hi;
        cp[d]      = f2bf(o0[r] * inv_l);
        cp[d + 32] = f2bf(o1[r] * inv_l);
    }
}

// ---------------- Dense GEMM + bias + residual ----------------
__global__ __launch_bounds__(256) void gemm_dense(
        const u16* __restrict__ A, const u16* __restrict__ W,
        const float* __restrict__ bias, const float* __restrict__ residual,
        float* __restrict__ out) {
    int lin = blockIdx.x;
    int sw = (lin & 7) * 32 + (lin >> 3);
    int bx = sw & 31;   // 32 m-blocks
    int by = sw >> 5;   // 8 n-blocks
    const int wave = threadIdx.x >> 6;
    const int lane = threadIdx.x & 63;
    const int la = lane & 31, hi = lane >> 5;
    const int m0 = bx * 128 + (wave >> 1) * 64;
    const int n0 = by * 128 + (wave & 1) * 64;
    const u16* ap = A + (size_t)(m0 + la) * K_DIM + hi * 8;
    const u16* bp = W + (size_t)(n0 + la) * K_DIM + hi * 8;
    f32x16 acc[2][2] = {};
    for (int k0 = 0; k0 < K_DIM; k0 += 16) {
        bf16x8 a0 = *reinterpret_cast<const bf16x8*>(ap + k0);
        bf16x8 a1 = *reinterpret_cast<const bf16x8*>(ap + 32 * K_DIM + k0);
        bf16x8 b0 = *reinterpret_cast<const bf16x8*>(bp + k0);
        bf16x8 b1 = *reinterpret_cast<const bf16x8*>(bp + 32 * K_DIM + k0);
        acc[0][0] = mfma32(a0, b0, acc[0][0]);
        acc[0][1] = mfma32(a0, b1, acc[0][1]);
        acc[1][0] = mfma32(a1, b0, acc[1][0]);
        acc[1][1] = mfma32(a1, b1, acc[1][1]);
    }
    #pragma unroll
    for (int mi = 0; mi < 2; ++mi)
    #pragma unroll
    for (int ni = 0; ni < 2; ++ni) {
        int c = n0 + ni * 32 + la;
        float bv = bias[c];
        #pragma unroll
        for (int r = 0; r < 16; ++r) {
            int m = m0 + mi * 32 + (r & 3) + 8 * (r >> 2) + 4 * hi;
            out[(size_t)m * HIDDEN + c] = acc[mi][ni][r] + bv + residual[(size_t)m * HIDDEN + c];
        }
    }
}

extern "C" void kernel_launch(void* const* d_in, const int* in_sizes, int n_in,
                              void* d_out, int out_size, void* d_ws, size_t ws_size,
                              hipStream_t stream) {
    const float* x        = (const float*)d_in[0];
    const float* residual = (const float*)d_in[1];
    const float* alibi    = (const float*)d_in[2];
    const float* W_qkv    = (const float*)d_in[4];
    const float* b_qkv    = (const float*)d_in[5];
    const float* W_dense  = (const float*)d_in[6];
    const float* b_dense  = (const float*)d_in[7];
    float* out = (float*)d_out;

    char* ws = (char*)d_ws;
    u16* xb  = (u16*)(ws);                 //  8 MB  x bf16
    u16* wqb = (u16*)(ws + 8388608);       //  6 MB  W_qkv bf16
    u16* wdb = (u16*)(ws + 14680064);      //  2 MB  W_dense bf16
    u16* q   = (u16*)(ws + 16777216);      //  8 MB  [B][H][S][64]
    u16* k   = (u16*)(ws + 25165824);      //  8 MB  [B][H][S][64]
    u16* vT  = (u16*)(ws + 33554432);      //  8 MB  [B][H][64][S]
    u16* ctx = (u16*)(ws + 41943040);      //  8 MB  [B*S][1024]

    cvt_f32_bf16<<<4096, 256, 0, stream>>>(x, xb, 4194304);
    cvt_f32_bf16<<<3072, 256, 0, stream>>>(W_qkv, wqb, 3145728);
    cvt_f32_bf16<<<1024, 256, 0, stream>>>(W_dense, wdb, 1048576);
    gemm_qkv<<<768, 256, 0, stream>>>(xb, wqb, b_qkv, q, k, vT);
    attn<<<512, 256, 0, stream>>>(q, k, vT, alibi, ctx);
    gemm_dense<<<256, 256, 0, stream>>>(ctx, wdb, b_dense, residual, out);
}

// Round 4
// 264.343 us; speedup vs baseline: 1.8305x; 1.0289x over previous
//
#include <hip/hip_runtime.h>
#include <hip/hip_bf16.h>

#define NUM_HEADS 16
#define HEAD_DIM  64
#define HIDDEN    1024
#define BATCH     2
#define SEQ       2048
#define K_DIM     1024
#define INV_NORM  0.125f
#define LOG2E     1.4426950408889634f
#define IN2       (INV_NORM * LOG2E)

typedef __attribute__((ext_vector_type(4)))  float f32x4;
typedef __attribute__((ext_vector_type(16))) float f32x16;
typedef __attribute__((ext_vector_type(8)))  short bf16x8;
typedef __attribute__((ext_vector_type(4)))  unsigned int u32x4;
typedef unsigned short u16;

__device__ inline u16 f2bf(float f) {
    __hip_bfloat16 h = __float2bfloat16(f);
    return __builtin_bit_cast(u16, h);
}
__device__ inline float bf2f(u16 u) {
    unsigned int v = ((unsigned int)u) << 16;
    return __builtin_bit_cast(float, v);
}
__device__ inline float fexp2(float x) { return __builtin_exp2f(x); }

__device__ inline f32x16 mfma32(bf16x8 a, bf16x8 b, f32x16 c) {
    return __builtin_amdgcn_mfma_f32_32x32x16_bf16(a, b, c, 0, 0, 0);
}

// ---------------- fp32 -> bf16 conversion ----------------
__global__ void cvt_f32_bf16(const float* __restrict__ in, u16* __restrict__ out, int n) {
    int i = (blockIdx.x * blockDim.x + threadIdx.x) * 4;
    if (i >= n) return;
    const float4 v = *reinterpret_cast<const float4*>(in + i);
    ushort4 o;
    o.x = f2bf(v.x); o.y = f2bf(v.y); o.z = f2bf(v.z); o.w = f2bf(v.w);
    *reinterpret_cast<ushort4*>(out + i) = o;
}

// ---------------- QKV GEMM: 128x128 block, 64x64/wave, 32x32x16 MFMA ----------------
__global__ __launch_bounds__(256) void gemm_qkv(
        const u16* __restrict__ A, const u16* __restrict__ W,
        const float* __restrict__ bias,
        u16* __restrict__ qo, u16* __restrict__ ko, u16* __restrict__ vTo) {
    int lin = blockIdx.x;
    int sw = (lin & 7) * 96 + (lin >> 3);
    int bx = sw & 31;   // 32 m-blocks
    int by = sw >> 5;   // 24 n-blocks
    const int wave = threadIdx.x >> 6;
    const int lane = threadIdx.x & 63;
    const int la = lane & 31, hi = lane >> 5;
    const int m0 = bx * 128 + (wave >> 1) * 64;
    const int n0 = by * 128 + (wave & 1) * 64;
    const u16* ap = A + (size_t)(m0 + la) * K_DIM + hi * 8;
    const u16* bp = W + (size_t)(n0 + la) * K_DIM + hi * 8;
    f32x16 acc[2][2] = {};
    for (int k0 = 0; k0 < K_DIM; k0 += 16) {
        bf16x8 a0 = *reinterpret_cast<const bf16x8*>(ap + k0);
        bf16x8 a1 = *reinterpret_cast<const bf16x8*>(ap + 32 * K_DIM + k0);
        bf16x8 b0 = *reinterpret_cast<const bf16x8*>(bp + k0);
        bf16x8 b1 = *reinterpret_cast<const bf16x8*>(bp + 32 * K_DIM + k0);
        acc[0][0] = mfma32(a0, b0, acc[0][0]);
        acc[0][1] = mfma32(a0, b1, acc[0][1]);
        acc[1][0] = mfma32(a1, b0, acc[1][0]);
        acc[1][1] = mfma32(a1, b1, acc[1][1]);
    }
    #pragma unroll
    for (int mi = 0; mi < 2; ++mi)
    #pragma unroll
    for (int ni = 0; ni < 2; ++ni) {
        int c = n0 + ni * 32 + la;          // fused col: h*192 + which*64 + d
        int h = c / 192, rem = c - h * 192;
        int which = rem >> 6, d = rem & 63;
        float bv = bias[c];
        #pragma unroll
        for (int r = 0; r < 16; ++r) {
            int m = m0 + mi * 32 + (r & 3) + 8 * (r >> 2) + 4 * hi;
            int bb = m >> 11, s = m & (SEQ - 1);
            int bh = bb * NUM_HEADS + h;
            u16 o = f2bf(acc[mi][ni][r] + bv);
            if (which == 0)      qo[((size_t)bh * SEQ + s) * HEAD_DIM + d] = o;
            else if (which == 1) ko[((size_t)bh * SEQ + s) * HEAD_DIM + d] = o;
            else                 vTo[((size_t)bh * HEAD_DIM + d) * SEQ + s] = o;
        }
    }
}

// ---------------- per-bh max ||k|| (for attention early-exit bound) ----------------
__global__ __launch_bounds__(256) void knorm_max(const u16* __restrict__ K,
                                                 float* __restrict__ kn) {
    __shared__ float red[256];
    const int bh = blockIdx.x;
    const u16* kp = K + (size_t)bh * SEQ * HEAD_DIM;
    float mx = 0.f;
    for (int s = threadIdx.x; s < SEQ; s += 256) {
        const bf16x8* row = reinterpret_cast<const bf16x8*>(kp + (size_t)s * HEAD_DIM);
        float ss = 0.f;
        #pragma unroll
        for (int j = 0; j < 8; ++j) {
            bf16x8 v = row[j];
            #pragma unroll
            for (int e = 0; e < 8; ++e) {
                float f = bf2f((u16)v[e]);
                ss = fmaf(f, f, ss);
            }
        }
        mx = fmaxf(mx, ss);
    }
    red[threadIdx.x] = mx;
    __syncthreads();
    for (int off = 128; off; off >>= 1) {
        if (threadIdx.x < (unsigned)off)
            red[threadIdx.x] = fmaxf(red[threadIdx.x], red[threadIdx.x + off]);
        __syncthreads();
    }
    if (threadIdx.x == 0) kn[bh] = sqrtf(red[0]);
}

// ---------------- Flash attention: swapped operands, reverse-k, early-exit ----------------
__global__ __launch_bounds__(256) void attn(
        const u16* __restrict__ Q, const u16* __restrict__ Kb,
        const u16* __restrict__ VT, const float* __restrict__ alibi,
        const float* __restrict__ kn, u16* __restrict__ ctx) {
    // 512 blocks: heavy-q first, heads interleaved for XCD balance
    const int lin = blockIdx.x;
    const int bh = lin & 31;
    const int qg = 15 - (lin >> 5);
    const int wave = threadIdx.x >> 6;
    const int lane = threadIdx.x & 63;
    const int la = lane & 31, hi = lane >> 5;
    const int qw = qg * 128 + wave * 32;
    const size_t sb = (size_t)bh * SEQ;

    const float slope2 = alibi[sb + 1] * LOG2E;   // alibi[bh][s] = slope*s exactly

    const u16* qp = Q + (sb + qw + la) * HEAD_DIM + hi * 8;
    bf16x8 qf0 = *reinterpret_cast<const bf16x8*>(qp);
    bf16x8 qf1 = *reinterpret_cast<const bf16x8*>(qp + 16);
    bf16x8 qf2 = *reinterpret_cast<const bf16x8*>(qp + 32);
    bf16x8 qf3 = *reinterpret_cast<const bf16x8*>(qp + 48);

    // per-wave max ||q|| for the skip bound
    float qss = 0.f;
    #pragma unroll
    for (int e = 0; e < 8; ++e) {
        float f;
        f = bf2f((u16)qf0[e]); qss = fmaf(f, f, qss);
        f = bf2f((u16)qf1[e]); qss = fmaf(f, f, qss);
        f = bf2f((u16)qf2[e]); qss = fmaf(f, f, qss);
        f = bf2f((u16)qf3[e]); qss = fmaf(f, f, qss);
    }
    qss += __shfl_xor(qss, 32);
    float qmx = qss;
    #pragma unroll
    for (int off = 1; off <= 16; off <<= 1) qmx = fmaxf(qmx, __shfl_xor(qmx, off));
    const float kb = sqrtf(qmx) * kn[bh] * IN2;   // log2-domain |qk| bound

    float skr2[16];
    #pragma unroll
    for (int r = 0; r < 16; ++r)
        skr2[r] = slope2 * (float)((r & 3) + 8 * (r >> 2) + 4 * hi);

    f32x16 o0 = {}, o1 = {};
    float m_i = -INFINITY, l_i = 0.f;

    const int ndiag = qw >> 5;
    for (int t = ndiag; t >= 0; --t) {
        const int k0 = t * 32;
        // early exit: bound on remaining tiles' scores vs current row max
        if (t != ndiag) {
            if (__all(kb + slope2 * (float)(k0 + 31) < m_i - 36.f)) break;
        }
        const u16* kp = Kb + (sb + k0 + la) * HEAD_DIM + hi * 8;
        bf16x8 kf0 = *reinterpret_cast<const bf16x8*>(kp);
        bf16x8 kf1 = *reinterpret_cast<const bf16x8*>(kp + 16);
        bf16x8 kf2 = *reinterpret_cast<const bf16x8*>(kp + 32);
        bf16x8 kf3 = *reinterpret_cast<const bf16x8*>(kp + 48);
        f32x16 sca = {}, scb = {};
        sca = mfma32(kf0, qf0, sca);
        scb = mfma32(kf1, qf1, scb);
        sca = mfma32(kf2, qf2, sca);
        scb = mfma32(kf3, qf3, scb);

        float s[16];
        const float base2 = slope2 * (float)k0;
        #pragma unroll
        for (int r = 0; r < 16; ++r)
            s[r] = fmaf(sca[r] + scb[r], IN2, base2 + skr2[r]);
        if (t == ndiag) {
            #pragma unroll
            for (int r = 0; r < 16; ++r) {
                int kr = (r & 3) + 8 * (r >> 2) + 4 * hi;
                if (kr > la) s[r] = -INFINITY;   // causal diagonal tile
            }
        }
        float ma = fmaxf(fmaxf(s[0], s[1]), fmaxf(s[2], s[3]));
        float mb = fmaxf(fmaxf(s[4], s[5]), fmaxf(s[6], s[7]));
        float mc = fmaxf(fmaxf(s[8], s[9]), fmaxf(s[10], s[11]));
        float md = fmaxf(fmaxf(s[12], s[13]), fmaxf(s[14], s[15]));
        float mx = fmaxf(fmaxf(ma, mb), fmaxf(mc, md));
        mx = fmaxf(mx, __shfl_xor(mx, 32));
        // defer-max (T13, log2 domain: 8 nats = 11.54 bits)
        if (!__all(mx <= m_i + 11.54f)) {
            float mnew = fmaxf(m_i, mx);
            float scl = fexp2(m_i - mnew);
            l_i *= scl;
            #pragma unroll
            for (int r = 0; r < 16; ++r) { o0[r] *= scl; o1[r] *= scl; }
            m_i = mnew;
        }
        #pragma unroll
        for (int r = 0; r < 16; ++r) s[r] = fexp2(s[r] - m_i);
        float sa = (s[0] + s[1]) + (s[2] + s[3]);
        float sbs = (s[4] + s[5]) + (s[6] + s[7]);
        float scs = (s[8] + s[9]) + (s[10] + s[11]);
        float sd = (s[12] + s[13]) + (s[14] + s[15]);
        float rs = (sa + sbs) + (scs + sd);
        rs += __shfl_xor(rs, 32);
        l_i += rs;

        // pack P quads to bf16 pairs; k of quad m = 8m + 4*hi + {0..3}
        unsigned int pk[8], swp[8];
        #pragma unroll
        for (int m = 0; m < 4; ++m) {
            pk[2 * m]     = (unsigned)f2bf(s[4 * m])     | ((unsigned)f2bf(s[4 * m + 1]) << 16);
            pk[2 * m + 1] = (unsigned)f2bf(s[4 * m + 2]) | ((unsigned)f2bf(s[4 * m + 3]) << 16);
        }
        #pragma unroll
        for (int i = 0; i < 8; ++i) swp[i] = __shfl_xor(pk[i], 32);
        u32x4 pb0, pb1;
        pb0[0] = hi ? swp[2] : pk[0];  pb0[1] = hi ? swp[3] : pk[1];
        pb0[2] = hi ? pk[2]  : swp[0]; pb0[3] = hi ? pk[3]  : swp[1];
        pb1[0] = hi ? swp[6] : pk[4];  pb1[1] = hi ? swp[7] : pk[5];
        pb1[2] = hi ? pk[6]  : swp[4]; pb1[3] = hi ? pk[7]  : swp[5];
        bf16x8 pf0 = __builtin_bit_cast(bf16x8, pb0);
        bf16x8 pf1 = __builtin_bit_cast(bf16x8, pb1);

        const u16* vp = VT + ((size_t)bh * HEAD_DIM + la) * SEQ + k0 + hi * 8;
        bf16x8 v00 = *reinterpret_cast<const bf16x8*>(vp);
        bf16x8 v01 = *reinterpret_cast<const bf16x8*>(vp + 16);
        bf16x8 v10 = *reinterpret_cast<const bf16x8*>(vp + 32 * SEQ);
        bf16x8 v11 = *reinterpret_cast<const bf16x8*>(vp + 32 * SEQ + 16);
        o0 = mfma32(v00, pf0, o0);
        o0 = mfma32(v01, pf1, o0);
        o1 = mfma32(v10, pf0, o1);
        o1 = mfma32(v11, pf1, o1);
    }

    const float inv_l = 1.0f / l_i;
    const int b = bh >> 4, h = bh & 15;
    u16* cp = ctx + ((size_t)(b * SEQ + qw + la)) * HIDDEN + h * HEAD_DIM;
    #pragma unroll
    for (int r = 0; r < 16; ++r) {
        int d = (r & 3) + 8 * (r >> 2) + 4 * hi;
        cp[d]      = f2bf(o0[r] * inv_l);
        cp[d + 32] = f2bf(o1[r] * inv_l);
    }
}

// ---------------- Dense GEMM + bias + residual ----------------
__global__ __launch_bounds__(256) void gemm_dense(
        const u16* __restrict__ A, const u16* __restrict__ W,
        const float* __restrict__ bias, const float* __restrict__ residual,
        float* __restrict__ out) {
    int lin = blockIdx.x;
    int sw = (lin & 7) * 32 + (lin >> 3);
    int bx = sw & 31;
    int by = sw >> 5;
    const int wave = threadIdx.x >> 6;
    const int lane = threadIdx.x & 63;
    const int la = lane & 31, hi = lane >> 5;
    const int m0 = bx * 128 + (wave >> 1) * 64;
    const int n0 = by * 128 + (wave & 1) * 64;
    const u16* ap = A + (size_t)(m0 + la) * K_DIM + hi * 8;
    const u16* bp = W + (size_t)(n0 + la) * K_DIM + hi * 8;
    f32x16 acc[2][2] = {};
    for (int k0 = 0; k0 < K_DIM; k0 += 16) {
        bf16x8 a0 = *reinterpret_cast<const bf16x8*>(ap + k0);
        bf16x8 a1 = *reinterpret_cast<const bf16x8*>(ap + 32 * K_DIM + k0);
        bf16x8 b0 = *reinterpret_cast<const bf16x8*>(bp + k0);
        bf16x8 b1 = *reinterpret_cast<const bf16x8*>(bp + 32 * K_DIM + k0);
        acc[0][0] = mfma32(a0, b0, acc[0][0]);
        acc[0][1] = mfma32(a0, b1, acc[0][1]);
        acc[1][0] = mfma32(a1, b0, acc[1][0]);
        acc[1][1] = mfma32(a1, b1, acc[1][1]);
    }
    #pragma unroll
    for (int mi = 0; mi < 2; ++mi)
    #pragma unroll
    for (int ni = 0; ni < 2; ++ni) {
        int c = n0 + ni * 32 + la;
        float bv = bias[c];
        #pragma unroll
        for (int r = 0; r < 16; ++r) {
            int m = m0 + mi * 32 + (r & 3) + 8 * (r >> 2) + 4 * hi;
            out[(size_t)m * HIDDEN + c] = acc[mi][ni][r] + bv + residual[(size_t)m * HIDDEN + c];
        }
    }
}

extern "C" void kernel_launch(void* const* d_in, const int* in_sizes, int n_in,
                              void* d_out, int out_size, void* d_ws, size_t ws_size,
                              hipStream_t stream) {
    const float* x        = (const float*)d_in[0];
    const float* residual = (const float*)d_in[1];
    const float* alibi    = (const float*)d_in[2];
    const float* W_qkv    = (const float*)d_in[4];
    const float* b_qkv    = (const float*)d_in[5];
    const float* W_dense  = (const float*)d_in[6];
    const float* b_dense  = (const float*)d_in[7];
    float* out = (float*)d_out;

    char* ws = (char*)d_ws;
    u16* xb  = (u16*)(ws);                 //  8 MB  x bf16
    u16* wqb = (u16*)(ws + 8388608);       //  6 MB  W_qkv bf16
    u16* wdb = (u16*)(ws + 14680064);      //  2 MB  W_dense bf16
    u16* q   = (u16*)(ws + 16777216);      //  8 MB  [B][H][S][64]
    u16* k   = (u16*)(ws + 25165824);      //  8 MB  [B][H][S][64]
    u16* vT  = (u16*)(ws + 33554432);      //  8 MB  [B][H][64][S]
    u16* ctx = (u16*)(ws + 41943040);      //  8 MB  [B*S][1024]
    float* kn = (float*)(ws + 50331648);   //  128 B per-bh max ||k||

    cvt_f32_bf16<<<4096, 256, 0, stream>>>(x, xb, 4194304);
    cvt_f32_bf16<<<3072, 256, 0, stream>>>(W_qkv, wqb, 3145728);
    cvt_f32_bf16<<<1024, 256, 0, stream>>>(W_dense, wdb, 1048576);
    gemm_qkv<<<768, 256, 0, stream>>>(xb, wqb, b_qkv, q, k, vT);
    knorm_max<<<32, 256, 0, stream>>>(k, kn);
    attn<<<512, 256, 0, stream>>>(q, k, vT, alibi, kn, ctx);
    gemm_dense<<<256, 256, 0, stream>>>(ctx, wdb, b_dense, residual, out);
}

// Round 5
// 212.030 us; speedup vs baseline: 2.2822x; 1.2467x over previous
//
#include <hip/hip_runtime.h>
#include <hip/hip_bf16.h>

#define NUM_HEADS 16
#define HEAD_DIM  64
#define HIDDEN    1024
#define BATCH     2
#define SEQ       2048
#define K_DIM     1024
#define INV_NORM  0.125f
#define LOG2E     1.4426950408889634f
#define IN2       (INV_NORM * LOG2E)

typedef __attribute__((ext_vector_type(4)))  float f32x4;
typedef __attribute__((ext_vector_type(16))) float f32x16;
typedef __attribute__((ext_vector_type(8)))  short bf16x8;
typedef __attribute__((ext_vector_type(4)))  unsigned int u32x4;
typedef unsigned short u16;

__device__ inline u16 f2bf(float f) {
    __hip_bfloat16 h = __float2bfloat16(f);
    return __builtin_bit_cast(u16, h);
}
__device__ inline float bf2f(u16 u) {
    unsigned int v = ((unsigned int)u) << 16;
    return __builtin_bit_cast(float, v);
}
__device__ inline float fexp2(float x) { return __builtin_exp2f(x); }

__device__ inline f32x16 mfma32(bf16x8 a, bf16x8 b, f32x16 c) {
    return __builtin_amdgcn_mfma_f32_32x32x16_bf16(a, b, c, 0, 0, 0);
}

// async global->LDS, 16B per lane; LDS dest is wave-uniform base + lane*16
__device__ inline void gl_lds16(const u16* g, u16* s) {
    __builtin_amdgcn_global_load_lds(
        (const __attribute__((address_space(1))) unsigned int*)g,
        (__attribute__((address_space(3))) unsigned int*)s, 16, 0, 0);
}

// ---------------- fp32 -> bf16 conversion ----------------
__global__ void cvt_f32_bf16(const float* __restrict__ in, u16* __restrict__ out, int n) {
    int i = (blockIdx.x * blockDim.x + threadIdx.x) * 4;
    if (i >= n) return;
    const float4 v = *reinterpret_cast<const float4*>(in + i);
    ushort4 o;
    o.x = f2bf(v.x); o.y = f2bf(v.y); o.z = f2bf(v.z); o.w = f2bf(v.w);
    *reinterpret_cast<ushort4*>(out + i) = o;
}

// ============ LDS-staged GEMM core: 128x128 tile, BK=64, 2-phase dbuf ============
// Swizzle: LDS(r, e) holds G(r, e ^ ((r&7)<<3)); ds_read applies same XOR -> conflict-free.
#define GEMM_CORE(A_, B_)                                                              \
    const int tid = threadIdx.x;                                                       \
    const int w = tid >> 6, l = tid & 63;                                              \
    const int la = l & 31, hi = l >> 5;                                                \
    const int wr = w >> 1, wc = w & 1;                                                 \
    const int kperm = (((l & 7) ^ (l >> 3)) << 3);                                     \
    const u16* gA = A_ + (size_t)(mblk + w * 32 + (l >> 3)) * K_DIM + kperm;           \
    const u16* gB = B_ + (size_t)(nblk + w * 32 + (l >> 3)) * K_DIM + kperm;           \
    const int sca = (la & 7) << 3;                                                     \
    f32x16 acc[2][2] = {};                                                             \
    _Pragma("unroll")                                                                  \
    for (int i = 0; i < 4; ++i) {                                                      \
        gl_lds16(gA + i * 8 * K_DIM, &As[0][(w * 32 + i * 8) * 64]);                   \
        gl_lds16(gB + i * 8 * K_DIM, &Bs[0][(w * 32 + i * 8) * 64]);                   \
    }                                                                                  \
    asm volatile("s_waitcnt vmcnt(0)" ::: "memory");                                   \
    __syncthreads();                                                                   \
    int buf = 0;                                                                       \
    for (int kt = 0; kt < 16; ++kt) {                                                  \
        if (kt < 15) {                                                                 \
            const int ko = (kt + 1) * 64;                                              \
            _Pragma("unroll")                                                          \
            for (int i = 0; i < 4; ++i) {                                              \
                gl_lds16(gA + i * 8 * K_DIM + ko, &As[buf ^ 1][(w * 32 + i * 8) * 64]);\
                gl_lds16(gB + i * 8 * K_DIM + ko, &Bs[buf ^ 1][(w * 32 + i * 8) * 64]);\
            }                                                                          \
        }                                                                              \
        const u16* pA = &As[buf][(wr * 64 + la) * 64];                                 \
        const u16* pB = &Bs[buf][(wc * 64 + la) * 64];                                 \
        _Pragma("unroll")                                                              \
        for (int kk = 0; kk < 4; ++kk) {                                               \
            const int co = (kk * 16 + hi * 8) ^ sca;                                   \
            bf16x8 a0 = *reinterpret_cast<const bf16x8*>(pA + co);                     \
            bf16x8 a1 = *reinterpret_cast<const bf16x8*>(pA + 32 * 64 + co);           \
            bf16x8 b0 = *reinterpret_cast<const bf16x8*>(pB + co);                     \
            bf16x8 b1 = *reinterpret_cast<const bf16x8*>(pB + 32 * 64 + co);           \
            acc[0][0] = mfma32(a0, b0, acc[0][0]);                                     \
            acc[0][1] = mfma32(a0, b1, acc[0][1]);                                     \
            acc[1][0] = mfma32(a1, b0, acc[1][0]);                                     \
            acc[1][1] = mfma32(a1, b1, acc[1][1]);                                     \
        }                                                                              \
        asm volatile("s_waitcnt vmcnt(0)" ::: "memory");                               \
        __syncthreads();                                                               \
        buf ^= 1;                                                                      \
    }

// ---------------- QKV GEMM + scatter to q/k/vT ----------------
__global__ __launch_bounds__(256) void gemm_qkv(
        const u16* __restrict__ A, const u16* __restrict__ W,
        const float* __restrict__ bias,
        u16* __restrict__ qo, u16* __restrict__ ko2, u16* __restrict__ vTo) {
    __shared__ u16 As[2][128 * 64];
    __shared__ u16 Bs[2][128 * 64];
    int lin = blockIdx.x;
    int sw = (lin & 7) * 96 + (lin >> 3);
    const int mblk = (sw & 31) * 128;
    const int nblk = (sw >> 5) * 128;
    GEMM_CORE(A, W)
    #pragma unroll
    for (int mi = 0; mi < 2; ++mi)
    #pragma unroll
    for (int ni = 0; ni < 2; ++ni) {
        int c = nblk + wc * 64 + ni * 32 + la;   // fused col: h*192 + which*64 + d
        int h = c / 192, rem = c - h * 192;
        int which = rem >> 6, d = rem & 63;
        float bv = bias[c];
        #pragma unroll
        for (int r = 0; r < 16; ++r) {
            int m = mblk + wr * 64 + mi * 32 + (r & 3) + 8 * (r >> 2) + 4 * hi;
            int bb = m >> 11, s = m & (SEQ - 1);
            int bh = bb * NUM_HEADS + h;
            u16 o = f2bf(acc[mi][ni][r] + bv);
            if (which == 0)      qo[((size_t)bh * SEQ + s) * HEAD_DIM + d] = o;
            else if (which == 1) ko2[((size_t)bh * SEQ + s) * HEAD_DIM + d] = o;
            else                 vTo[((size_t)bh * HEAD_DIM + d) * SEQ + s] = o;
        }
    }
}

// ---------------- Dense GEMM + bias + residual ----------------
__global__ __launch_bounds__(256) void gemm_dense(
        const u16* __restrict__ A, const u16* __restrict__ W,
        const float* __restrict__ bias, const float* __restrict__ residual,
        float* __restrict__ out) {
    __shared__ u16 As[2][128 * 64];
    __shared__ u16 Bs[2][128 * 64];
    int lin = blockIdx.x;
    int sw = (lin & 7) * 32 + (lin >> 3);
    const int mblk = (sw & 31) * 128;
    const int nblk = (sw >> 5) * 128;
    GEMM_CORE(A, W)
    #pragma unroll
    for (int mi = 0; mi < 2; ++mi)
    #pragma unroll
    for (int ni = 0; ni < 2; ++ni) {
        int c = nblk + wc * 64 + ni * 32 + la;
        float bv = bias[c];
        #pragma unroll
        for (int r = 0; r < 16; ++r) {
            int m = mblk + wr * 64 + mi * 32 + (r & 3) + 8 * (r >> 2) + 4 * hi;
            out[(size_t)m * HIDDEN + c] = acc[mi][ni][r] + bv + residual[(size_t)m * HIDDEN + c];
        }
    }
}

// ---------------- per-bh max ||k|| (for attention early-exit bound) ----------------
__global__ __launch_bounds__(256) void knorm_max(const u16* __restrict__ K,
                                                 float* __restrict__ kn) {
    __shared__ float red[256];
    const int bh = blockIdx.x;
    const u16* kp = K + (size_t)bh * SEQ * HEAD_DIM;
    float mx = 0.f;
    for (int s = threadIdx.x; s < SEQ; s += 256) {
        const bf16x8* row = reinterpret_cast<const bf16x8*>(kp + (size_t)s * HEAD_DIM);
        float ss = 0.f;
        #pragma unroll
        for (int j = 0; j < 8; ++j) {
            bf16x8 v = row[j];
            #pragma unroll
            for (int e = 0; e < 8; ++e) {
                float f = bf2f((u16)v[e]);
                ss = fmaf(f, f, ss);
            }
        }
        mx = fmaxf(mx, ss);
    }
    red[threadIdx.x] = mx;
    __syncthreads();
    for (int off = 128; off; off >>= 1) {
        if (threadIdx.x < (unsigned)off)
            red[threadIdx.x] = fmaxf(red[threadIdx.x], red[threadIdx.x + off]);
        __syncthreads();
    }
    if (threadIdx.x == 0) kn[bh] = sqrtf(red[0]);
}

// ---------------- Flash attention: swapped operands, reverse-k, early-exit ----------------
__global__ __launch_bounds__(256) void attn(
        const u16* __restrict__ Q, const u16* __restrict__ Kb,
        const u16* __restrict__ VT, const float* __restrict__ alibi,
        const float* __restrict__ kn, u16* __restrict__ ctx) {
    const int lin = blockIdx.x;
    const int bh = lin & 31;
    const int qg = 15 - (lin >> 5);
    const int wave = threadIdx.x >> 6;
    const int lane = threadIdx.x & 63;
    const int la = lane & 31, hi = lane >> 5;
    const int qw = qg * 128 + wave * 32;
    const size_t sb = (size_t)bh * SEQ;

    const float slope2 = alibi[sb + 1] * LOG2E;

    const u16* qp = Q + (sb + qw + la) * HEAD_DIM + hi * 8;
    bf16x8 qf0 = *reinterpret_cast<const bf16x8*>(qp);
    bf16x8 qf1 = *reinterpret_cast<const bf16x8*>(qp + 16);
    bf16x8 qf2 = *reinterpret_cast<const bf16x8*>(qp + 32);
    bf16x8 qf3 = *reinterpret_cast<const bf16x8*>(qp + 48);

    float qss = 0.f;
    #pragma unroll
    for (int e = 0; e < 8; ++e) {
        float f;
        f = bf2f((u16)qf0[e]); qss = fmaf(f, f, qss);
        f = bf2f((u16)qf1[e]); qss = fmaf(f, f, qss);
        f = bf2f((u16)qf2[e]); qss = fmaf(f, f, qss);
        f = bf2f((u16)qf3[e]); qss = fmaf(f, f, qss);
    }
    qss += __shfl_xor(qss, 32);
    float qmx = qss;
    #pragma unroll
    for (int off = 1; off <= 16; off <<= 1) qmx = fmaxf(qmx, __shfl_xor(qmx, off));
    const float kb = sqrtf(qmx) * kn[bh] * IN2;

    float skr2[16];
    #pragma unroll
    for (int r = 0; r < 16; ++r)
        skr2[r] = slope2 * (float)((r & 3) + 8 * (r >> 2) + 4 * hi);

    f32x16 o0 = {}, o1 = {};
    float m_i = -INFINITY, l_i = 0.f;

    const int ndiag = qw >> 5;
    for (int t = ndiag; t >= 0; --t) {
        const int k0 = t * 32;
        if (t != ndiag) {
            if (__all(kb + slope2 * (float)(k0 + 31) < m_i - 36.f)) break;
        }
        const u16* kp = Kb + (sb + k0 + la) * HEAD_DIM + hi * 8;
        bf16x8 kf0 = *reinterpret_cast<const bf16x8*>(kp);
        bf16x8 kf1 = *reinterpret_cast<const bf16x8*>(kp + 16);
        bf16x8 kf2 = *reinterpret_cast<const bf16x8*>(kp + 32);
        bf16x8 kf3 = *reinterpret_cast<const bf16x8*>(kp + 48);
        f32x16 sca = {}, scb = {};
        sca = mfma32(kf0, qf0, sca);
        scb = mfma32(kf1, qf1, scb);
        sca = mfma32(kf2, qf2, sca);
        scb = mfma32(kf3, qf3, scb);

        float s[16];
        const float base2 = slope2 * (float)k0;
        #pragma unroll
        for (int r = 0; r < 16; ++r)
            s[r] = fmaf(sca[r] + scb[r], IN2, base2 + skr2[r]);
        if (t == ndiag) {
            #pragma unroll
            for (int r = 0; r < 16; ++r) {
                int kr = (r & 3) + 8 * (r >> 2) + 4 * hi;
                if (kr > la) s[r] = -INFINITY;
            }
        }
        float ma = fmaxf(fmaxf(s[0], s[1]), fmaxf(s[2], s[3]));
        float mb = fmaxf(fmaxf(s[4], s[5]), fmaxf(s[6], s[7]));
        float mc = fmaxf(fmaxf(s[8], s[9]), fmaxf(s[10], s[11]));
        float md = fmaxf(fmaxf(s[12], s[13]), fmaxf(s[14], s[15]));
        float mx = fmaxf(fmaxf(ma, mb), fmaxf(mc, md));
        mx = fmaxf(mx, __shfl_xor(mx, 32));
        if (!__all(mx <= m_i + 11.54f)) {
            float mnew = fmaxf(m_i, mx);
            float scl = fexp2(m_i - mnew);
            l_i *= scl;
            #pragma unroll
            for (int r = 0; r < 16; ++r) { o0[r] *= scl; o1[r] *= scl; }
            m_i = mnew;
        }
        #pragma unroll
        for (int r = 0; r < 16; ++r) s[r] = fexp2(s[r] - m_i);
        float sa = (s[0] + s[1]) + (s[2] + s[3]);
        float sbs = (s[4] + s[5]) + (s[6] + s[7]);
        float scs = (s[8] + s[9]) + (s[10] + s[11]);
        float sd = (s[12] + s[13]) + (s[14] + s[15]);
        float rs = (sa + sbs) + (scs + sd);
        rs += __shfl_xor(rs, 32);
        l_i += rs;

        unsigned int pk[8], swp[8];
        #pragma unroll
        for (int m = 0; m < 4; ++m) {
            pk[2 * m]     = (unsigned)f2bf(s[4 * m])     | ((unsigned)f2bf(s[4 * m + 1]) << 16);
            pk[2 * m + 1] = (unsigned)f2bf(s[4 * m + 2]) | ((unsigned)f2bf(s[4 * m + 3]) << 16);
        }
        #pragma unroll
        for (int i = 0; i < 8; ++i) swp[i] = __shfl_xor(pk[i], 32);
        u32x4 pb0, pb1;
        pb0[0] = hi ? swp[2] : pk[0];  pb0[1] = hi ? swp[3] : pk[1];
        pb0[2] = hi ? pk[2]  : swp[0]; pb0[3] = hi ? pk[3]  : swp[1];
        pb1[0] = hi ? swp[6] : pk[4];  pb1[1] = hi ? swp[7] : pk[5];
        pb1[2] = hi ? pk[6]  : swp[4]; pb1[3] = hi ? pk[7]  : swp[5];
        bf16x8 pf0 = __builtin_bit_cast(bf16x8, pb0);
        bf16x8 pf1 = __builtin_bit_cast(bf16x8, pb1);

        const u16* vp = VT + ((size_t)bh * HEAD_DIM + la) * SEQ + k0 + hi * 8;
        bf16x8 v00 = *reinterpret_cast<const bf16x8*>(vp);
        bf16x8 v01 = *reinterpret_cast<const bf16x8*>(vp + 16);
        bf16x8 v10 = *reinterpret_cast<const bf16x8*>(vp + 32 * SEQ);
        bf16x8 v11 = *reinterpret_cast<const bf16x8*>(vp + 32 * SEQ + 16);
        o0 = mfma32(v00, pf0, o0);
        o0 = mfma32(v01, pf1, o0);
        o1 = mfma32(v10, pf0, o1);
        o1 = mfma32(v11, pf1, o1);
    }

    const float inv_l = 1.0f / l_i;
    const int b = bh >> 4, h = bh & 15;
    u16* cp = ctx + ((size_t)(b * SEQ + qw + la)) * HIDDEN + h * HEAD_DIM;
    #pragma unroll
    for (int r = 0; r < 16; ++r) {
        int d = (r & 3) + 8 * (r >> 2) + 4 * hi;
        cp[d]      = f2bf(o0[r] * inv_l);
        cp[d + 32] = f2bf(o1[r] * inv_l);
    }
}

extern "C" void kernel_launch(void* const* d_in, const int* in_sizes, int n_in,
                              void* d_out, int out_size, void* d_ws, size_t ws_size,
                              hipStream_t stream) {
    const float* x        = (const float*)d_in[0];
    const float* residual = (const float*)d_in[1];
    const float* alibi    = (const float*)d_in[2];
    const float* W_qkv    = (const float*)d_in[4];
    const float* b_qkv    = (const float*)d_in[5];
    const float* W_dense  = (const float*)d_in[6];
    const float* b_dense  = (const float*)d_in[7];
    float* out = (float*)d_out;

    char* ws = (char*)d_ws;
    u16* xb  = (u16*)(ws);                 //  8 MB  x bf16
    u16* wqb = (u16*)(ws + 8388608);       //  6 MB  W_qkv bf16
    u16* wdb = (u16*)(ws + 14680064);      //  2 MB  W_dense bf16
    u16* q   = (u16*)(ws + 16777216);      //  8 MB  [B][H][S][64]
    u16* k   = (u16*)(ws + 25165824);      //  8 MB  [B][H][S][64]
    u16* vT  = (u16*)(ws + 33554432);      //  8 MB  [B][H][64][S]
    u16* ctx = (u16*)(ws + 41943040);      //  8 MB  [B*S][1024]
    float* kn = (float*)(ws + 50331648);   //  128 B per-bh max ||k||

    cvt_f32_bf16<<<4096, 256, 0, stream>>>(x, xb, 4194304);
    cvt_f32_bf16<<<3072, 256, 0, stream>>>(W_qkv, wqb, 3145728);
    cvt_f32_bf16<<<1024, 256, 0, stream>>>(W_dense, wdb, 1048576);
    gemm_qkv<<<768, 256, 0, stream>>>(xb, wqb, b_qkv, q, k, vT);
    knorm_max<<<32, 256, 0, stream>>>(k, kn);
    attn<<<512, 256, 0, stream>>>(q, k, vT, alibi, kn, ctx);
    gemm_dense<<<256, 256, 0, stream>>>(ctx, wdb, b_dense, residual, out);
}

// Round 6
// 185.687 us; speedup vs baseline: 2.6059x; 1.1419x over previous
//
#include <hip/hip_runtime.h>
#include <hip/hip_bf16.h>

#define NUM_HEADS 16
#define HEAD_DIM  64
#define HIDDEN    1024
#define BATCH     2
#define SEQ       2048
#define K_DIM     1024
#define INV_NORM  0.125f
#define LOG2E     1.4426950408889634f
#define IN2       (INV_NORM * LOG2E)

typedef __attribute__((ext_vector_type(4)))  float f32x4;
typedef __attribute__((ext_vector_type(16))) float f32x16;
typedef __attribute__((ext_vector_type(8)))  short bf16x8;
typedef __attribute__((ext_vector_type(4)))  unsigned int u32x4;
typedef unsigned short u16;

__device__ inline u16 f2bf(float f) {
    __hip_bfloat16 h = __float2bfloat16(f);
    return __builtin_bit_cast(u16, h);
}
__device__ inline float bf2f(u16 u) {
    unsigned int v = ((unsigned int)u) << 16;
    return __builtin_bit_cast(float, v);
}
__device__ inline float fexp2(float x) { return __builtin_exp2f(x); }

__device__ inline f32x16 mfma32(bf16x8 a, bf16x8 b, f32x16 c) {
    return __builtin_amdgcn_mfma_f32_32x32x16_bf16(a, b, c, 0, 0, 0);
}

// async global->LDS, 16B per lane; LDS dest is wave-uniform base + lane*16
__device__ inline void gl_lds16(const u16* g, u16* s) {
    __builtin_amdgcn_global_load_lds(
        (const __attribute__((address_space(1))) unsigned int*)g,
        (__attribute__((address_space(3))) unsigned int*)s, 16, 0, 0);
}

// ---------------- fp32 -> bf16 conversion ----------------
__global__ void cvt_f32_bf16(const float* __restrict__ in, u16* __restrict__ out, int n) {
    int i = (blockIdx.x * blockDim.x + threadIdx.x) * 4;
    if (i >= n) return;
    const float4 v = *reinterpret_cast<const float4*>(in + i);
    ushort4 o;
    o.x = f2bf(v.x); o.y = f2bf(v.y); o.z = f2bf(v.z); o.w = f2bf(v.w);
    *reinterpret_cast<ushort4*>(out + i) = o;
}

// ============ LDS-staged GEMM core: 128x128 tile, BK=64, 2-phase dbuf ============
#define GEMM_CORE(A_, B_)                                                              \
    const int tid = threadIdx.x;                                                       \
    const int w = tid >> 6, l = tid & 63;                                              \
    const int la = l & 31, hi = l >> 5;                                                \
    const int wr = w >> 1, wc = w & 1;                                                 \
    const int kperm = (((l & 7) ^ (l >> 3)) << 3);                                     \
    const u16* gA = A_ + (size_t)(mblk + w * 32 + (l >> 3)) * K_DIM + kperm;           \
    const u16* gB = B_ + (size_t)(nblk + w * 32 + (l >> 3)) * K_DIM + kperm;           \
    const int sca = (la & 7) << 3;                                                     \
    f32x16 acc[2][2] = {};                                                             \
    _Pragma("unroll")                                                                  \
    for (int i = 0; i < 4; ++i) {                                                      \
        gl_lds16(gA + i * 8 * K_DIM, &As[0][(w * 32 + i * 8) * 64]);                   \
        gl_lds16(gB + i * 8 * K_DIM, &Bs[0][(w * 32 + i * 8) * 64]);                   \
    }                                                                                  \
    asm volatile("s_waitcnt vmcnt(0)" ::: "memory");                                   \
    __syncthreads();                                                                   \
    int buf = 0;                                                                       \
    for (int kt = 0; kt < 16; ++kt) {                                                  \
        if (kt < 15) {                                                                 \
            const int ko = (kt + 1) * 64;                                              \
            _Pragma("unroll")                                                          \
            for (int i = 0; i < 4; ++i) {                                              \
                gl_lds16(gA + i * 8 * K_DIM + ko, &As[buf ^ 1][(w * 32 + i * 8) * 64]);\
                gl_lds16(gB + i * 8 * K_DIM + ko, &Bs[buf ^ 1][(w * 32 + i * 8) * 64]);\
            }                                                                          \
        }                                                                              \
        const u16* pA = &As[buf][(wr * 64 + la) * 64];                                 \
        const u16* pB = &Bs[buf][(wc * 64 + la) * 64];                                 \
        _Pragma("unroll")                                                              \
        for (int kk = 0; kk < 4; ++kk) {                                               \
            const int co = (kk * 16 + hi * 8) ^ sca;                                   \
            bf16x8 a0 = *reinterpret_cast<const bf16x8*>(pA + co);                     \
            bf16x8 a1 = *reinterpret_cast<const bf16x8*>(pA + 32 * 64 + co);           \
            bf16x8 b0 = *reinterpret_cast<const bf16x8*>(pB + co);                     \
            bf16x8 b1 = *reinterpret_cast<const bf16x8*>(pB + 32 * 64 + co);           \
            acc[0][0] = mfma32(a0, b0, acc[0][0]);                                     \
            acc[0][1] = mfma32(a0, b1, acc[0][1]);                                     \
            acc[1][0] = mfma32(a1, b0, acc[1][0]);                                     \
            acc[1][1] = mfma32(a1, b1, acc[1][1]);                                     \
        }                                                                              \
        asm volatile("s_waitcnt vmcnt(0)" ::: "memory");                               \
        __syncthreads();                                                               \
        buf ^= 1;                                                                      \
    }

// ---------------- QKV GEMM + scatter to q/k/vT ----------------
__global__ __launch_bounds__(256) void gemm_qkv(
        const u16* __restrict__ A, const u16* __restrict__ W,
        const float* __restrict__ bias,
        u16* __restrict__ qo, u16* __restrict__ ko2, u16* __restrict__ vTo) {
    __shared__ u16 As[2][128 * 64];
    __shared__ u16 Bs[2][128 * 64];
    int lin = blockIdx.x;
    int sw = (lin & 7) * 96 + (lin >> 3);
    const int mblk = (sw & 31) * 128;
    const int nblk = (sw >> 5) * 128;
    GEMM_CORE(A, W)
    #pragma unroll
    for (int mi = 0; mi < 2; ++mi)
    #pragma unroll
    for (int ni = 0; ni < 2; ++ni) {
        int c = nblk + wc * 64 + ni * 32 + la;   // fused col: h*192 + which*64 + d
        int h = c / 192, rem = c - h * 192;
        int which = rem >> 6, d = rem & 63;
        float bv = bias[c];
        #pragma unroll
        for (int r = 0; r < 16; ++r) {
            int m = mblk + wr * 64 + mi * 32 + (r & 3) + 8 * (r >> 2) + 4 * hi;
            int bb = m >> 11, s = m & (SEQ - 1);
            int bh = bb * NUM_HEADS + h;
            u16 o = f2bf(acc[mi][ni][r] + bv);
            if (which == 0)      qo[((size_t)bh * SEQ + s) * HEAD_DIM + d] = o;
            else if (which == 1) ko2[((size_t)bh * SEQ + s) * HEAD_DIM + d] = o;
            else                 vTo[((size_t)bh * HEAD_DIM + d) * SEQ + s] = o;
        }
    }
}

// ---------------- Dense GEMM + bias + residual ----------------
__global__ __launch_bounds__(256) void gemm_dense(
        const u16* __restrict__ A, const u16* __restrict__ W,
        const float* __restrict__ bias, const float* __restrict__ residual,
        float* __restrict__ out) {
    __shared__ u16 As[2][128 * 64];
    __shared__ u16 Bs[2][128 * 64];
    int lin = blockIdx.x;
    int sw = (lin & 7) * 32 + (lin >> 3);
    const int mblk = (sw & 31) * 128;
    const int nblk = (sw >> 5) * 128;
    GEMM_CORE(A, W)
    #pragma unroll
    for (int mi = 0; mi < 2; ++mi)
    #pragma unroll
    for (int ni = 0; ni < 2; ++ni) {
        int c = nblk + wc * 64 + ni * 32 + la;
        float bv = bias[c];
        #pragma unroll
        for (int r = 0; r < 16; ++r) {
            int m = mblk + wr * 64 + mi * 32 + (r & 3) + 8 * (r >> 2) + 4 * hi;
            out[(size_t)m * HIDDEN + c] = acc[mi][ni][r] + bv + residual[(size_t)m * HIDDEN + c];
        }
    }
}

// ---------------- per-bh max ||k|| (for attention early-exit bound) ----------------
__global__ __launch_bounds__(256) void knorm_max(const u16* __restrict__ K,
                                                 float* __restrict__ kn) {
    __shared__ float red[256];
    const int bh = blockIdx.x;
    const u16* kp = K + (size_t)bh * SEQ * HEAD_DIM;
    float mx = 0.f;
    for (int s = threadIdx.x; s < SEQ; s += 256) {
        const bf16x8* row = reinterpret_cast<const bf16x8*>(kp + (size_t)s * HEAD_DIM);
        float ss = 0.f;
        #pragma unroll
        for (int j = 0; j < 8; ++j) {
            bf16x8 v = row[j];
            #pragma unroll
            for (int e = 0; e < 8; ++e) {
                float f = bf2f((u16)v[e]);
                ss = fmaf(f, f, ss);
            }
        }
        mx = fmaxf(mx, ss);
    }
    red[threadIdx.x] = mx;
    __syncthreads();
    for (int off = 128; off; off >>= 1) {
        if (threadIdx.x < (unsigned)off)
            red[threadIdx.x] = fmaxf(red[threadIdx.x], red[threadIdx.x + off]);
        __syncthreads();
    }
    if (threadIdx.x == 0) kn[bh] = sqrtf(red[0]);
}

// ---------------- Flash attention: 4-way split-K per 32-row q-tile ----------------
// Block = 4 waves = one q-tile. Wave w processes key-tiles qt-w, qt-w-4, ...
// (reverse-interleaved: each wave sees near-diagonal first -> strong local max
// for the early-exit bound). Partial (o,m,l) merged via LDS.
__global__ __launch_bounds__(256) void attn(
        const u16* __restrict__ Q, const u16* __restrict__ Kb,
        const u16* __restrict__ VT, const float* __restrict__ alibi,
        const float* __restrict__ kn, u16* __restrict__ ctx) {
    __shared__ float o_l[4][64][33];   // wave x d x q, padded (+1) -> 2-way free
    __shared__ float ml[4][2][32];     // m, l per wave per q-row
    const int lin = blockIdx.x;
    const int bh = lin & 31;
    const int qt = 63 - (lin >> 5);    // heavy q-tiles dispatch first
    const int wave = threadIdx.x >> 6;
    const int lane = threadIdx.x & 63;
    const int la = lane & 31, hi = lane >> 5;
    const int qw = qt * 32;
    const size_t sb = (size_t)bh * SEQ;

    const float slope2 = alibi[sb + 1] * LOG2E;

    const u16* qp = Q + (sb + qw + la) * HEAD_DIM + hi * 8;
    bf16x8 qf0 = *reinterpret_cast<const bf16x8*>(qp);
    bf16x8 qf1 = *reinterpret_cast<const bf16x8*>(qp + 16);
    bf16x8 qf2 = *reinterpret_cast<const bf16x8*>(qp + 32);
    bf16x8 qf3 = *reinterpret_cast<const bf16x8*>(qp + 48);

    float qss = 0.f;
    #pragma unroll
    for (int e = 0; e < 8; ++e) {
        float f;
        f = bf2f((u16)qf0[e]); qss = fmaf(f, f, qss);
        f = bf2f((u16)qf1[e]); qss = fmaf(f, f, qss);
        f = bf2f((u16)qf2[e]); qss = fmaf(f, f, qss);
        f = bf2f((u16)qf3[e]); qss = fmaf(f, f, qss);
    }
    qss += __shfl_xor(qss, 32);
    float qmx = qss;
    #pragma unroll
    for (int off = 1; off <= 16; off <<= 1) qmx = fmaxf(qmx, __shfl_xor(qmx, off));
    const float kb = sqrtf(qmx) * kn[bh] * IN2;

    float skr2[16];
    #pragma unroll
    for (int r = 0; r < 16; ++r)
        skr2[r] = slope2 * (float)((r & 3) + 8 * (r >> 2) + 4 * hi);

    f32x16 o0 = {}, o1 = {};
    float m_i = -INFINITY, l_i = 0.f;

    for (int t = qt - wave; t >= 0; t -= 4) {
        const int k0 = t * 32;
        // early exit (first iter: m_i=-inf -> never breaks); bound monotone in k
        if (__all(kb + slope2 * (float)(k0 + 31) < m_i - 36.f)) break;
        const u16* kp = Kb + (sb + k0 + la) * HEAD_DIM + hi * 8;
        bf16x8 kf0 = *reinterpret_cast<const bf16x8*>(kp);
        bf16x8 kf1 = *reinterpret_cast<const bf16x8*>(kp + 16);
        bf16x8 kf2 = *reinterpret_cast<const bf16x8*>(kp + 32);
        bf16x8 kf3 = *reinterpret_cast<const bf16x8*>(kp + 48);
        f32x16 sca = {}, scb = {};
        sca = mfma32(kf0, qf0, sca);
        scb = mfma32(kf1, qf1, scb);
        sca = mfma32(kf2, qf2, sca);
        scb = mfma32(kf3, qf3, scb);

        float s[16];
        const float base2 = slope2 * (float)k0;
        #pragma unroll
        for (int r = 0; r < 16; ++r)
            s[r] = fmaf(sca[r] + scb[r], IN2, base2 + skr2[r]);
        if (t == qt) {   // diagonal tile (only wave 0 reaches it)
            #pragma unroll
            for (int r = 0; r < 16; ++r) {
                int kr = (r & 3) + 8 * (r >> 2) + 4 * hi;
                if (kr > la) s[r] = -INFINITY;
            }
        }
        float ma = fmaxf(fmaxf(s[0], s[1]), fmaxf(s[2], s[3]));
        float mb = fmaxf(fmaxf(s[4], s[5]), fmaxf(s[6], s[7]));
        float mc = fmaxf(fmaxf(s[8], s[9]), fmaxf(s[10], s[11]));
        float md = fmaxf(fmaxf(s[12], s[13]), fmaxf(s[14], s[15]));
        float mx = fmaxf(fmaxf(ma, mb), fmaxf(mc, md));
        mx = fmaxf(mx, __shfl_xor(mx, 32));
        if (!__all(mx <= m_i + 11.54f)) {
            float mnew = fmaxf(m_i, mx);
            float scl = fexp2(m_i - mnew);
            l_i *= scl;
            #pragma unroll
            for (int r = 0; r < 16; ++r) { o0[r] *= scl; o1[r] *= scl; }
            m_i = mnew;
        }
        #pragma unroll
        for (int r = 0; r < 16; ++r) s[r] = fexp2(s[r] - m_i);
        float sa = (s[0] + s[1]) + (s[2] + s[3]);
        float sbs = (s[4] + s[5]) + (s[6] + s[7]);
        float scs = (s[8] + s[9]) + (s[10] + s[11]);
        float sd = (s[12] + s[13]) + (s[14] + s[15]);
        float rs = (sa + sbs) + (scs + sd);
        rs += __shfl_xor(rs, 32);
        l_i += rs;

        unsigned int pk[8], swp[8];
        #pragma unroll
        for (int m = 0; m < 4; ++m) {
            pk[2 * m]     = (unsigned)f2bf(s[4 * m])     | ((unsigned)f2bf(s[4 * m + 1]) << 16);
            pk[2 * m + 1] = (unsigned)f2bf(s[4 * m + 2]) | ((unsigned)f2bf(s[4 * m + 3]) << 16);
        }
        #pragma unroll
        for (int i = 0; i < 8; ++i) swp[i] = __shfl_xor(pk[i], 32);
        u32x4 pb0, pb1;
        pb0[0] = hi ? swp[2] : pk[0];  pb0[1] = hi ? swp[3] : pk[1];
        pb0[2] = hi ? pk[2]  : swp[0]; pb0[3] = hi ? pk[3]  : swp[1];
        pb1[0] = hi ? swp[6] : pk[4];  pb1[1] = hi ? swp[7] : pk[5];
        pb1[2] = hi ? pk[6]  : swp[4]; pb1[3] = hi ? pk[7]  : swp[5];
        bf16x8 pf0 = __builtin_bit_cast(bf16x8, pb0);
        bf16x8 pf1 = __builtin_bit_cast(bf16x8, pb1);

        const u16* vp = VT + ((size_t)bh * HEAD_DIM + la) * SEQ + k0 + hi * 8;
        bf16x8 v00 = *reinterpret_cast<const bf16x8*>(vp);
        bf16x8 v01 = *reinterpret_cast<const bf16x8*>(vp + 16);
        bf16x8 v10 = *reinterpret_cast<const bf16x8*>(vp + 32 * SEQ);
        bf16x8 v11 = *reinterpret_cast<const bf16x8*>(vp + 32 * SEQ + 16);
        o0 = mfma32(v00, pf0, o0);
        o0 = mfma32(v01, pf1, o0);
        o1 = mfma32(v10, pf0, o1);
        o1 = mfma32(v11, pf1, o1);
    }

    // ---- write partials to LDS ----
    if (hi == 0) { ml[wave][0][la] = m_i; ml[wave][1][la] = l_i; }
    #pragma unroll
    for (int r = 0; r < 16; ++r) {
        int d = (r & 3) + 8 * (r >> 2) + 4 * hi;
        o_l[wave][d][la]      = o0[r];
        o_l[wave][d + 32][la] = o1[r];
    }
    __syncthreads();

    // ---- combine: thread = (q, 8-wide d slab) ----
    const int q  = threadIdx.x >> 3;
    const int d0 = (threadIdx.x & 7) * 8;
    float m0w = ml[0][0][q], m1w = ml[1][0][q], m2w = ml[2][0][q], m3w = ml[3][0][q];
    float M = fmaxf(fmaxf(m0w, m1w), fmaxf(m2w, m3w));
    float s0 = fexp2(m0w - M), s1 = fexp2(m1w - M);
    float s2 = fexp2(m2w - M), s3 = fexp2(m3w - M);
    float L = s0 * ml[0][1][q] + s1 * ml[1][1][q] + s2 * ml[2][1][q] + s3 * ml[3][1][q];
    float inv = 1.0f / L;
    unsigned int packed[4];
    #pragma unroll
    for (int e2 = 0; e2 < 4; ++e2) {
        float Oa = s0 * o_l[0][d0 + 2 * e2][q] + s1 * o_l[1][d0 + 2 * e2][q]
                 + s2 * o_l[2][d0 + 2 * e2][q] + s3 * o_l[3][d0 + 2 * e2][q];
        float Ob = s0 * o_l[0][d0 + 2 * e2 + 1][q] + s1 * o_l[1][d0 + 2 * e2 + 1][q]
                 + s2 * o_l[2][d0 + 2 * e2 + 1][q] + s3 * o_l[3][d0 + 2 * e2 + 1][q];
        packed[e2] = (unsigned)f2bf(Oa * inv) | ((unsigned)f2bf(Ob * inv) << 16);
    }
    const int b = bh >> 4, h = bh & 15;
    u32x4 pv; pv[0] = packed[0]; pv[1] = packed[1]; pv[2] = packed[2]; pv[3] = packed[3];
    *reinterpret_cast<u32x4*>(
        &ctx[((size_t)(b * SEQ + qw + q)) * HIDDEN + h * HEAD_DIM + d0]) = pv;
}

extern "C" void kernel_launch(void* const* d_in, const int* in_sizes, int n_in,
                              void* d_out, int out_size, void* d_ws, size_t ws_size,
                              hipStream_t stream) {
    const float* x        = (const float*)d_in[0];
    const float* residual = (const float*)d_in[1];
    const float* alibi    = (const float*)d_in[2];
    const float* W_qkv    = (const float*)d_in[4];
    const float* b_qkv    = (const float*)d_in[5];
    const float* W_dense  = (const float*)d_in[6];
    const float* b_dense  = (const float*)d_in[7];
    float* out = (float*)d_out;

    char* ws = (char*)d_ws;
    u16* xb  = (u16*)(ws);                 //  8 MB  x bf16
    u16* wqb = (u16*)(ws + 8388608);       //  6 MB  W_qkv bf16
    u16* wdb = (u16*)(ws + 14680064);      //  2 MB  W_dense bf16
    u16* q   = (u16*)(ws + 16777216);      //  8 MB  [B][H][S][64]
    u16* k   = (u16*)(ws + 25165824);      //  8 MB  [B][H][S][64]
    u16* vT  = (u16*)(ws + 33554432);      //  8 MB  [B][H][64][S]
    u16* ctx = (u16*)(ws + 41943040);      //  8 MB  [B*S][1024]
    float* kn = (float*)(ws + 50331648);   //  128 B per-bh max ||k||

    cvt_f32_bf16<<<4096, 256, 0, stream>>>(x, xb, 4194304);
    cvt_f32_bf16<<<3072, 256, 0, stream>>>(W_qkv, wqb, 3145728);
    cvt_f32_bf16<<<1024, 256, 0, stream>>>(W_dense, wdb, 1048576);
    gemm_qkv<<<768, 256, 0, stream>>>(xb, wqb, b_qkv, q, k, vT);
    knorm_max<<<32, 256, 0, stream>>>(k, kn);
    attn<<<2048, 256, 0, stream>>>(q, k, vT, alibi, kn, ctx);
    gemm_dense<<<256, 256, 0, stream>>>(ctx, wdb, b_dense, residual, out);
}

// Round 7
// 168.281 us; speedup vs baseline: 2.8755x; 1.1034x over previous
//
#include <hip/hip_runtime.h>
#include <hip/hip_bf16.h>

#define NUM_HEADS 16
#define HEAD_DIM  64
#define HIDDEN    1024
#define BATCH     2
#define SEQ       2048
#define K_DIM     1024
#define INV_NORM  0.125f
#define LOG2E     1.4426950408889634f
#define IN2       (INV_NORM * LOG2E)
#define N_ITEMS   2048

typedef __attribute__((ext_vector_type(4)))  float f32x4;
typedef __attribute__((ext_vector_type(16))) float f32x16;
typedef __attribute__((ext_vector_type(8)))  short bf16x8;
typedef __attribute__((ext_vector_type(4)))  unsigned int u32x4;
typedef unsigned short u16;

__device__ inline u16 f2bf(float f) {
    __hip_bfloat16 h = __float2bfloat16(f);
    return __builtin_bit_cast(u16, h);
}
__device__ inline float bf2f(u16 u) {
    unsigned int v = ((unsigned int)u) << 16;
    return __builtin_bit_cast(float, v);
}
__device__ inline float fexp2(float x) { return __builtin_exp2f(x); }

__device__ inline f32x16 mfma32(bf16x8 a, bf16x8 b, f32x16 c) {
    return __builtin_amdgcn_mfma_f32_32x32x16_bf16(a, b, c, 0, 0, 0);
}

// async global->LDS, 16B per lane; LDS dest is wave-uniform base + lane*16
__device__ inline void gl_lds16(const u16* g, u16* s) {
    __builtin_amdgcn_global_load_lds(
        (const __attribute__((address_space(1))) unsigned int*)g,
        (__attribute__((address_space(3))) unsigned int*)s, 16, 0, 0);
}

// ---------------- fused fp32 -> bf16 conversion (x, W_qkv, W_dense) ----------------
__global__ __launch_bounds__(256) void cvt_all(
        const float* __restrict__ x, const float* __restrict__ wq,
        const float* __restrict__ wd,
        u16* __restrict__ xb, u16* __restrict__ wqb, u16* __restrict__ wdb) {
    int i = (blockIdx.x * 256 + threadIdx.x) * 4;   // 8388608 elements total
    const float* s; u16* d; int off;
    if (i < 4194304)      { s = x;  d = xb;  off = i; }
    else if (i < 7340032) { s = wq; d = wqb; off = i - 4194304; }
    else                  { s = wd; d = wdb; off = i - 7340032; }
    const float4 v = *reinterpret_cast<const float4*>(s + off);
    ushort4 o;
    o.x = f2bf(v.x); o.y = f2bf(v.y); o.z = f2bf(v.z); o.w = f2bf(v.w);
    *reinterpret_cast<ushort4*>(d + off) = o;
}

// ============ LDS-staged GEMM core: 128x128 tile, BK=64, 2-phase dbuf ============
#define GEMM_CORE(A_, B_)                                                              \
    const int tid = threadIdx.x;                                                       \
    const int w = tid >> 6, l = tid & 63;                                              \
    const int la = l & 31, hi = l >> 5;                                                \
    const int wr = w >> 1, wc = w & 1;                                                 \
    const int kperm = (((l & 7) ^ (l >> 3)) << 3);                                     \
    const u16* gA = A_ + (size_t)(mblk + w * 32 + (l >> 3)) * K_DIM + kperm;           \
    const u16* gB = B_ + (size_t)(nblk + w * 32 + (l >> 3)) * K_DIM + kperm;           \
    const int sca = (la & 7) << 3;                                                     \
    f32x16 acc[2][2] = {};                                                             \
    _Pragma("unroll")                                                                  \
    for (int i = 0; i < 4; ++i) {                                                      \
        gl_lds16(gA + i * 8 * K_DIM, &As[0][(w * 32 + i * 8) * 64]);                   \
        gl_lds16(gB + i * 8 * K_DIM, &Bs[0][(w * 32 + i * 8) * 64]);                   \
    }                                                                                  \
    asm volatile("s_waitcnt vmcnt(0)" ::: "memory");                                   \
    __syncthreads();                                                                   \
    int buf = 0;                                                                       \
    for (int kt = 0; kt < 16; ++kt) {                                                  \
        if (kt < 15) {                                                                 \
            const int ko = (kt + 1) * 64;                                              \
            _Pragma("unroll")                                                          \
            for (int i = 0; i < 4; ++i) {                                              \
                gl_lds16(gA + i * 8 * K_DIM + ko, &As[buf ^ 1][(w * 32 + i * 8) * 64]);\
                gl_lds16(gB + i * 8 * K_DIM + ko, &Bs[buf ^ 1][(w * 32 + i * 8) * 64]);\
            }                                                                          \
        }                                                                              \
        const u16* pA = &As[buf][(wr * 64 + la) * 64];                                 \
        const u16* pB = &Bs[buf][(wc * 64 + la) * 64];                                 \
        _Pragma("unroll")                                                              \
        for (int kk = 0; kk < 4; ++kk) {                                               \
            const int co = (kk * 16 + hi * 8) ^ sca;                                   \
            bf16x8 a0 = *reinterpret_cast<const bf16x8*>(pA + co);                     \
            bf16x8 a1 = *reinterpret_cast<const bf16x8*>(pA + 32 * 64 + co);           \
            bf16x8 b0 = *reinterpret_cast<const bf16x8*>(pB + co);                     \
            bf16x8 b1 = *reinterpret_cast<const bf16x8*>(pB + 32 * 64 + co);           \
            acc[0][0] = mfma32(a0, b0, acc[0][0]);                                     \
            acc[0][1] = mfma32(a0, b1, acc[0][1]);                                     \
            acc[1][0] = mfma32(a1, b0, acc[1][0]);                                     \
            acc[1][1] = mfma32(a1, b1, acc[1][1]);                                     \
        }                                                                              \
        asm volatile("s_waitcnt vmcnt(0)" ::: "memory");                               \
        __syncthreads();                                                               \
        buf ^= 1;                                                                      \
    }

// ---------------- QKV GEMM + scatter to q/k/vT ----------------
__global__ __launch_bounds__(256) void gemm_qkv(
        const u16* __restrict__ A, const u16* __restrict__ W,
        const float* __restrict__ bias,
        u16* __restrict__ qo, u16* __restrict__ ko2, u16* __restrict__ vTo) {
    __shared__ u16 As[2][128 * 64];
    __shared__ u16 Bs[2][128 * 64];
    int lin = blockIdx.x;
    int sw = (lin & 7) * 96 + (lin >> 3);
    const int mblk = (sw & 31) * 128;
    const int nblk = (sw >> 5) * 128;
    GEMM_CORE(A, W)
    #pragma unroll
    for (int mi = 0; mi < 2; ++mi)
    #pragma unroll
    for (int ni = 0; ni < 2; ++ni) {
        int c = nblk + wc * 64 + ni * 32 + la;   // fused col: h*192 + which*64 + d
        int h = c / 192, rem = c - h * 192;
        int which = rem >> 6, d = rem & 63;
        float bv = bias[c];
        #pragma unroll
        for (int r = 0; r < 16; ++r) {
            int m = mblk + wr * 64 + mi * 32 + (r & 3) + 8 * (r >> 2) + 4 * hi;
            int bb = m >> 11, s = m & (SEQ - 1);
            int bh = bb * NUM_HEADS + h;
            u16 o = f2bf(acc[mi][ni][r] + bv);
            if (which == 0)      qo[((size_t)bh * SEQ + s) * HEAD_DIM + d] = o;
            else if (which == 1) ko2[((size_t)bh * SEQ + s) * HEAD_DIM + d] = o;
            else                 vTo[((size_t)bh * HEAD_DIM + d) * SEQ + s] = o;
        }
    }
}

// ---------------- Dense GEMM + bias + residual ----------------
__global__ __launch_bounds__(256) void gemm_dense(
        const u16* __restrict__ A, const u16* __restrict__ W,
        const float* __restrict__ bias, const float* __restrict__ residual,
        float* __restrict__ out) {
    __shared__ u16 As[2][128 * 64];
    __shared__ u16 Bs[2][128 * 64];
    int lin = blockIdx.x;
    int sw = (lin & 7) * 32 + (lin >> 3);
    const int mblk = (sw & 31) * 128;
    const int nblk = (sw >> 5) * 128;
    GEMM_CORE(A, W)
    #pragma unroll
    for (int mi = 0; mi < 2; ++mi)
    #pragma unroll
    for (int ni = 0; ni < 2; ++ni) {
        int c = nblk + wc * 64 + ni * 32 + la;
        float bv = bias[c];
        #pragma unroll
        for (int r = 0; r < 16; ++r) {
            int m = mblk + wr * 64 + mi * 32 + (r & 3) + 8 * (r >> 2) + 4 * hi;
            out[(size_t)m * HIDDEN + c] = acc[mi][ni][r] + bv + residual[(size_t)m * HIDDEN + c];
        }
    }
}

// ---------------- per-bh max ||k||, and reset attn work counter ----------------
__global__ __launch_bounds__(256) void knorm_max(const u16* __restrict__ K,
                                                 float* __restrict__ kn,
                                                 unsigned int* __restrict__ ctr) {
    if (blockIdx.x == 0 && threadIdx.x == 0) *ctr = 0;   // stream-ordered before attn
    __shared__ float red[256];
    const int bh = blockIdx.x;
    const u16* kp = K + (size_t)bh * SEQ * HEAD_DIM;
    float mx = 0.f;
    for (int s = threadIdx.x; s < SEQ; s += 256) {
        const bf16x8* row = reinterpret_cast<const bf16x8*>(kp + (size_t)s * HEAD_DIM);
        float ss = 0.f;
        #pragma unroll
        for (int j = 0; j < 8; ++j) {
            bf16x8 v = row[j];
            #pragma unroll
            for (int e = 0; e < 8; ++e) {
                float f = bf2f((u16)v[e]);
                ss = fmaf(f, f, ss);
            }
        }
        mx = fmaxf(mx, ss);
    }
    red[threadIdx.x] = mx;
    __syncthreads();
    for (int off = 128; off; off >>= 1) {
        if (threadIdx.x < (unsigned)off)
            red[threadIdx.x] = fmaxf(red[threadIdx.x], red[threadIdx.x + off]);
        __syncthreads();
    }
    if (threadIdx.x == 0) kn[bh] = sqrtf(red[0]);
}

// ---------------- Flash attention: persistent blocks + work-stealing ----------------
// Item = (bh, qt): one 32-row q-tile, 4-way split-K across the block's waves.
__global__ __launch_bounds__(256) void attn(
        const u16* __restrict__ Q, const u16* __restrict__ Kb,
        const u16* __restrict__ VT, const float* __restrict__ alibi,
        const float* __restrict__ kn, u16* __restrict__ ctx,
        unsigned int* __restrict__ ctr) {
    __shared__ float o_l[4][64][33];
    __shared__ float ml[4][2][32];
    __shared__ unsigned int s_idx;
    const int wave = threadIdx.x >> 6;
    const int lane = threadIdx.x & 63;
    const int la = lane & 31, hi = lane >> 5;

    for (;;) {
        if (threadIdx.x == 0) s_idx = atomicAdd(ctr, 1u);
        __syncthreads();                     // publish s_idx; protect o_l reuse
        const unsigned int idx = s_idx;
        if (idx >= N_ITEMS) return;
        const int bh = idx & 31;
        const int qt = 63 - (int)(idx >> 5); // heavy q-tiles first
        const int qw = qt * 32;
        const size_t sb = (size_t)bh * SEQ;

        const float slope2 = alibi[sb + 1] * LOG2E;

        const u16* qp = Q + (sb + qw + la) * HEAD_DIM + hi * 8;
        bf16x8 qf0 = *reinterpret_cast<const bf16x8*>(qp);
        bf16x8 qf1 = *reinterpret_cast<const bf16x8*>(qp + 16);
        bf16x8 qf2 = *reinterpret_cast<const bf16x8*>(qp + 32);
        bf16x8 qf3 = *reinterpret_cast<const bf16x8*>(qp + 48);

        float qss = 0.f;
        #pragma unroll
        for (int e = 0; e < 8; ++e) {
            float f;
            f = bf2f((u16)qf0[e]); qss = fmaf(f, f, qss);
            f = bf2f((u16)qf1[e]); qss = fmaf(f, f, qss);
            f = bf2f((u16)qf2[e]); qss = fmaf(f, f, qss);
            f = bf2f((u16)qf3[e]); qss = fmaf(f, f, qss);
        }
        qss += __shfl_xor(qss, 32);
        float qmx = qss;
        #pragma unroll
        for (int off = 1; off <= 16; off <<= 1) qmx = fmaxf(qmx, __shfl_xor(qmx, off));
        const float kb = sqrtf(qmx) * kn[bh] * IN2;

        float skr2[16];
        #pragma unroll
        for (int r = 0; r < 16; ++r)
            skr2[r] = slope2 * (float)((r & 3) + 8 * (r >> 2) + 4 * hi);

        f32x16 o0 = {}, o1 = {};
        float m_i = -INFINITY, l_i = 0.f;

        for (int t = qt - wave; t >= 0; t -= 4) {
            const int k0 = t * 32;
            if (__all(kb + slope2 * (float)(k0 + 31) < m_i - 36.f)) break;
            const u16* kp = Kb + (sb + k0 + la) * HEAD_DIM + hi * 8;
            bf16x8 kf0 = *reinterpret_cast<const bf16x8*>(kp);
            bf16x8 kf1 = *reinterpret_cast<const bf16x8*>(kp + 16);
            bf16x8 kf2 = *reinterpret_cast<const bf16x8*>(kp + 32);
            bf16x8 kf3 = *reinterpret_cast<const bf16x8*>(kp + 48);
            f32x16 sca = {}, scb = {};
            sca = mfma32(kf0, qf0, sca);
            scb = mfma32(kf1, qf1, scb);
            sca = mfma32(kf2, qf2, sca);
            scb = mfma32(kf3, qf3, scb);

            // issue V loads early: latency hides under softmax
            const u16* vp = VT + ((size_t)bh * HEAD_DIM + la) * SEQ + k0 + hi * 8;
            bf16x8 v00 = *reinterpret_cast<const bf16x8*>(vp);
            bf16x8 v01 = *reinterpret_cast<const bf16x8*>(vp + 16);
            bf16x8 v10 = *reinterpret_cast<const bf16x8*>(vp + 32 * SEQ);
            bf16x8 v11 = *reinterpret_cast<const bf16x8*>(vp + 32 * SEQ + 16);

            float s[16];
            const float base2 = slope2 * (float)k0;
            #pragma unroll
            for (int r = 0; r < 16; ++r)
                s[r] = fmaf(sca[r] + scb[r], IN2, base2 + skr2[r]);
            if (t == qt) {   // diagonal tile (wave 0 only)
                #pragma unroll
                for (int r = 0; r < 16; ++r) {
                    int kr = (r & 3) + 8 * (r >> 2) + 4 * hi;
                    if (kr > la) s[r] = -INFINITY;
                }
            }
            float ma = fmaxf(fmaxf(s[0], s[1]), fmaxf(s[2], s[3]));
            float mb = fmaxf(fmaxf(s[4], s[5]), fmaxf(s[6], s[7]));
            float mc = fmaxf(fmaxf(s[8], s[9]), fmaxf(s[10], s[11]));
            float md = fmaxf(fmaxf(s[12], s[13]), fmaxf(s[14], s[15]));
            float mx = fmaxf(fmaxf(ma, mb), fmaxf(mc, md));
            mx = fmaxf(mx, __shfl_xor(mx, 32));
            if (!__all(mx <= m_i + 11.54f)) {
                float mnew = fmaxf(m_i, mx);
                float scl = fexp2(m_i - mnew);
                l_i *= scl;
                #pragma unroll
                for (int r = 0; r < 16; ++r) { o0[r] *= scl; o1[r] *= scl; }
                m_i = mnew;
            }
            #pragma unroll
            for (int r = 0; r < 16; ++r) s[r] = fexp2(s[r] - m_i);
            float sa = (s[0] + s[1]) + (s[2] + s[3]);
            float sbs = (s[4] + s[5]) + (s[6] + s[7]);
            float scs = (s[8] + s[9]) + (s[10] + s[11]);
            float sd = (s[12] + s[13]) + (s[14] + s[15]);
            float rs = (sa + sbs) + (scs + sd);
            rs += __shfl_xor(rs, 32);
            l_i += rs;

            unsigned int pk[8], swp[8];
            #pragma unroll
            for (int m = 0; m < 4; ++m) {
                pk[2 * m]     = (unsigned)f2bf(s[4 * m])     | ((unsigned)f2bf(s[4 * m + 1]) << 16);
                pk[2 * m + 1] = (unsigned)f2bf(s[4 * m + 2]) | ((unsigned)f2bf(s[4 * m + 3]) << 16);
            }
            #pragma unroll
            for (int i = 0; i < 8; ++i) swp[i] = __shfl_xor(pk[i], 32);
            u32x4 pb0, pb1;
            pb0[0] = hi ? swp[2] : pk[0];  pb0[1] = hi ? swp[3] : pk[1];
            pb0[2] = hi ? pk[2]  : swp[0]; pb0[3] = hi ? pk[3]  : swp[1];
            pb1[0] = hi ? swp[6] : pk[4];  pb1[1] = hi ? swp[7] : pk[5];
            pb1[2] = hi ? pk[6]  : swp[4]; pb1[3] = hi ? pk[7]  : swp[5];
            bf16x8 pf0 = __builtin_bit_cast(bf16x8, pb0);
            bf16x8 pf1 = __builtin_bit_cast(bf16x8, pb1);

            o0 = mfma32(v00, pf0, o0);
            o0 = mfma32(v01, pf1, o0);
            o1 = mfma32(v10, pf0, o1);
            o1 = mfma32(v11, pf1, o1);
        }

        // ---- write partials to LDS ----
        if (hi == 0) { ml[wave][0][la] = m_i; ml[wave][1][la] = l_i; }
        #pragma unroll
        for (int r = 0; r < 16; ++r) {
            int d = (r & 3) + 8 * (r >> 2) + 4 * hi;
            o_l[wave][d][la]      = o0[r];
            o_l[wave][d + 32][la] = o1[r];
        }
        __syncthreads();

        // ---- combine: thread = (q, 8-wide d slab) ----
        const int q  = threadIdx.x >> 3;
        const int d0 = (threadIdx.x & 7) * 8;
        float m0w = ml[0][0][q], m1w = ml[1][0][q], m2w = ml[2][0][q], m3w = ml[3][0][q];
        float M = fmaxf(fmaxf(m0w, m1w), fmaxf(m2w, m3w));
        float s0 = fexp2(m0w - M), s1 = fexp2(m1w - M);
        float s2 = fexp2(m2w - M), s3 = fexp2(m3w - M);
        float L = s0 * ml[0][1][q] + s1 * ml[1][1][q] + s2 * ml[2][1][q] + s3 * ml[3][1][q];
        float inv = 1.0f / L;
        unsigned int packed[4];
        #pragma unroll
        for (int e2 = 0; e2 < 4; ++e2) {
            float Oa = s0 * o_l[0][d0 + 2 * e2][q] + s1 * o_l[1][d0 + 2 * e2][q]
                     + s2 * o_l[2][d0 + 2 * e2][q] + s3 * o_l[3][d0 + 2 * e2][q];
            float Ob = s0 * o_l[0][d0 + 2 * e2 + 1][q] + s1 * o_l[1][d0 + 2 * e2 + 1][q]
                     + s2 * o_l[2][d0 + 2 * e2 + 1][q] + s3 * o_l[3][d0 + 2 * e2 + 1][q];
            packed[e2] = (unsigned)f2bf(Oa * inv) | ((unsigned)f2bf(Ob * inv) << 16);
        }
        const int b = bh >> 4, h = bh & 15;
        u32x4 pv; pv[0] = packed[0]; pv[1] = packed[1]; pv[2] = packed[2]; pv[3] = packed[3];
        *reinterpret_cast<u32x4*>(
            &ctx[((size_t)(b * SEQ + qw + q)) * HIDDEN + h * HEAD_DIM + d0]) = pv;
    }
}

extern "C" void kernel_launch(void* const* d_in, const int* in_sizes, int n_in,
                              void* d_out, int out_size, void* d_ws, size_t ws_size,
                              hipStream_t stream) {
    const float* x        = (const float*)d_in[0];
    const float* residual = (const float*)d_in[1];
    const float* alibi    = (const float*)d_in[2];
    const float* W_qkv    = (const float*)d_in[4];
    const float* b_qkv    = (const float*)d_in[5];
    const float* W_dense  = (const float*)d_in[6];
    const float* b_dense  = (const float*)d_in[7];
    float* out = (float*)d_out;

    char* ws = (char*)d_ws;
    u16* xb  = (u16*)(ws);                 //  8 MB  x bf16
    u16* wqb = (u16*)(ws + 8388608);       //  6 MB  W_qkv bf16
    u16* wdb = (u16*)(ws + 14680064);      //  2 MB  W_dense bf16
    u16* q   = (u16*)(ws + 16777216);      //  8 MB  [B][H][S][64]
    u16* k   = (u16*)(ws + 25165824);      //  8 MB  [B][H][S][64]
    u16* vT  = (u16*)(ws + 33554432);      //  8 MB  [B][H][64][S]
    u16* ctx = (u16*)(ws + 41943040);      //  8 MB  [B*S][1024]
    float* kn = (float*)(ws + 50331648);   //  128 B per-bh max ||k||
    unsigned int* ctr = (unsigned int*)(ws + 50331648 + 256);

    cvt_all<<<8192, 256, 0, stream>>>(x, W_qkv, W_dense, xb, wqb, wdb);
    gemm_qkv<<<768, 256, 0, stream>>>(xb, wqb, b_qkv, q, k, vT);
    knorm_max<<<32, 256, 0, stream>>>(k, kn, ctr);
    attn<<<1024, 256, 0, stream>>>(q, k, vT, alibi, kn, ctx, ctr);
    gemm_dense<<<256, 256, 0, stream>>>(ctx, wdb, b_dense, residual, out);
}

// Round 8
// 150.678 us; speedup vs baseline: 3.2114x; 1.1168x over previous
//
#include <hip/hip_runtime.h>
#include <hip/hip_bf16.h>

#define NUM_HEADS 16
#define HEAD_DIM  64
#define HIDDEN    1024
#define BATCH     2
#define SEQ       2048
#define K_DIM     1024
#define INV_NORM  0.125f
#define LOG2E     1.4426950408889634f
#define IN2       (INV_NORM * LOG2E)
#define N_ITEMS   2048

typedef __attribute__((ext_vector_type(4)))  float f32x4;
typedef __attribute__((ext_vector_type(16))) float f32x16;
typedef __attribute__((ext_vector_type(8)))  short bf16x8;
typedef __attribute__((ext_vector_type(4)))  unsigned int u32x4;
typedef unsigned short u16;

__device__ inline u16 f2bf(float f) {
    __hip_bfloat16 h = __float2bfloat16(f);
    return __builtin_bit_cast(u16, h);
}
__device__ inline float bf2f(u16 u) {
    unsigned int v = ((unsigned int)u) << 16;
    return __builtin_bit_cast(float, v);
}
__device__ inline float fexp2(float x) { return __builtin_exp2f(x); }

__device__ inline f32x16 mfma32(bf16x8 a, bf16x8 b, f32x16 c) {
    return __builtin_amdgcn_mfma_f32_32x32x16_bf16(a, b, c, 0, 0, 0);
}

// async global->LDS, 16B per lane; LDS dest is wave-uniform base + lane*16
__device__ inline void gl_lds16(const u16* g, u16* s) {
    __builtin_amdgcn_global_load_lds(
        (const __attribute__((address_space(1))) unsigned int*)g,
        (__attribute__((address_space(3))) unsigned int*)s, 16, 0, 0);
}

// ---------------- fused fp32 -> bf16 conversion (x, W_qkv, W_dense) ----------------
__global__ __launch_bounds__(256) void cvt_all(
        const float* __restrict__ x, const float* __restrict__ wq,
        const float* __restrict__ wd,
        u16* __restrict__ xb, u16* __restrict__ wqb, u16* __restrict__ wdb) {
    int i = (blockIdx.x * 256 + threadIdx.x) * 4;   // 8388608 elements total
    const float* s; u16* d; int off;
    if (i < 4194304)      { s = x;  d = xb;  off = i; }
    else if (i < 7340032) { s = wq; d = wqb; off = i - 4194304; }
    else                  { s = wd; d = wdb; off = i - 7340032; }
    const float4 v = *reinterpret_cast<const float4*>(s + off);
    ushort4 o;
    o.x = f2bf(v.x); o.y = f2bf(v.y); o.z = f2bf(v.z); o.w = f2bf(v.w);
    *reinterpret_cast<ushort4*>(d + off) = o;
}

// ============ LDS-staged GEMM core: 128x128 tile, BK=64, single-buffer (m97 2-barrier) ============
// LDS(row, slot) = G(row, slot ^ (row&7)); read XORs slot with (row&7) -> conflict-reduced.
#define GEMM_CORE(A_, B_)                                                              \
    const int tid = threadIdx.x;                                                       \
    const int w = tid >> 6, l = tid & 63;                                              \
    const int la = l & 31, hi = l >> 5;                                                \
    const int wr = w >> 1, wc = w & 1;                                                 \
    const int kperm = (((l & 7) ^ (l >> 3)) << 3);                                     \
    const u16* gA = A_ + (size_t)(mblk + w * 32 + (l >> 3)) * K_DIM + kperm;           \
    const u16* gB = B_ + (size_t)(nblk + w * 32 + (l >> 3)) * K_DIM + kperm;           \
    const int sca = (la & 7) << 3;                                                     \
    f32x16 acc[2][2] = {};                                                             \
    for (int kt = 0; kt < 16; ++kt) {                                                  \
        const int ko = kt * 64;                                                        \
        _Pragma("unroll")                                                              \
        for (int i = 0; i < 4; ++i) {                                                  \
            gl_lds16(gA + i * 8 * K_DIM + ko, &As[(w * 32 + i * 8) * 64]);             \
            gl_lds16(gB + i * 8 * K_DIM + ko, &Bs[(w * 32 + i * 8) * 64]);             \
        }                                                                              \
        asm volatile("s_waitcnt vmcnt(0)" ::: "memory");                               \
        __syncthreads();                                                               \
        const u16* pA = &As[(wr * 64 + la) * 64];                                      \
        const u16* pB = &Bs[(wc * 64 + la) * 64];                                      \
        _Pragma("unroll")                                                              \
        for (int kk = 0; kk < 4; ++kk) {                                               \
            const int co = (kk * 16 + hi * 8) ^ sca;                                   \
            bf16x8 a0 = *reinterpret_cast<const bf16x8*>(pA + co);                     \
            bf16x8 a1 = *reinterpret_cast<const bf16x8*>(pA + 32 * 64 + co);           \
            bf16x8 b0 = *reinterpret_cast<const bf16x8*>(pB + co);                     \
            bf16x8 b1 = *reinterpret_cast<const bf16x8*>(pB + 32 * 64 + co);           \
            acc[0][0] = mfma32(a0, b0, acc[0][0]);                                     \
            acc[0][1] = mfma32(a0, b1, acc[0][1]);                                     \
            acc[1][0] = mfma32(a1, b0, acc[1][0]);                                     \
            acc[1][1] = mfma32(a1, b1, acc[1][1]);                                     \
        }                                                                              \
        __syncthreads();                                                               \
    }

// ---------------- QKV GEMM + scatter to q/k/vT ----------------
__global__ __launch_bounds__(256) void gemm_qkv(
        const u16* __restrict__ A, const u16* __restrict__ W,
        const float* __restrict__ bias,
        u16* __restrict__ qo, u16* __restrict__ ko2, u16* __restrict__ vTo) {
    __shared__ u16 As[128 * 64];
    __shared__ u16 Bs[128 * 64];
    int lin = blockIdx.x;
    int sw = (lin & 7) * 96 + (lin >> 3);
    const int mblk = (sw & 31) * 128;
    const int nblk = (sw >> 5) * 128;
    GEMM_CORE(A, W)
    #pragma unroll
    for (int mi = 0; mi < 2; ++mi)
    #pragma unroll
    for (int ni = 0; ni < 2; ++ni) {
        int c = nblk + wc * 64 + ni * 32 + la;   // fused col: h*192 + which*64 + d
        int h = c / 192, rem = c - h * 192;
        int which = rem >> 6, d = rem & 63;
        float bv = bias[c];
        #pragma unroll
        for (int r = 0; r < 16; ++r) {
            int m = mblk + wr * 64 + mi * 32 + (r & 3) + 8 * (r >> 2) + 4 * hi;
            int bb = m >> 11, s = m & (SEQ - 1);
            int bh = bb * NUM_HEADS + h;
            u16 o = f2bf(acc[mi][ni][r] + bv);
            if (which == 0)      qo[((size_t)bh * SEQ + s) * HEAD_DIM + d] = o;
            else if (which == 1) ko2[((size_t)bh * SEQ + s) * HEAD_DIM + d] = o;
            else                 vTo[((size_t)bh * HEAD_DIM + d) * SEQ + s] = o;
        }
    }
}

// ---------------- Dense GEMM + bias + residual ----------------
__global__ __launch_bounds__(256) void gemm_dense(
        const u16* __restrict__ A, const u16* __restrict__ W,
        const float* __restrict__ bias, const float* __restrict__ residual,
        float* __restrict__ out) {
    __shared__ u16 As[128 * 64];
    __shared__ u16 Bs[128 * 64];
    int lin = blockIdx.x;
    int sw = (lin & 7) * 32 + (lin >> 3);
    const int mblk = (sw & 31) * 128;
    const int nblk = (sw >> 5) * 128;
    GEMM_CORE(A, W)
    #pragma unroll
    for (int mi = 0; mi < 2; ++mi)
    #pragma unroll
    for (int ni = 0; ni < 2; ++ni) {
        int c = nblk + wc * 64 + ni * 32 + la;
        float bv = bias[c];
        #pragma unroll
        for (int r = 0; r < 16; ++r) {
            int m = mblk + wr * 64 + mi * 32 + (r & 3) + 8 * (r >> 2) + 4 * hi;
            out[(size_t)m * HIDDEN + c] = acc[mi][ni][r] + bv + residual[(size_t)m * HIDDEN + c];
        }
    }
}

// ---------------- per-bh max ||k||, and reset attn work counter ----------------
__global__ __launch_bounds__(256) void knorm_max(const u16* __restrict__ K,
                                                 float* __restrict__ kn,
                                                 unsigned int* __restrict__ ctr) {
    if (blockIdx.x == 0 && threadIdx.x == 0) *ctr = 0;   // stream-ordered before attn
    __shared__ float red[256];
    const int bh = blockIdx.x;
    const u16* kp = K + (size_t)bh * SEQ * HEAD_DIM;
    float mx = 0.f;
    for (int s = threadIdx.x; s < SEQ; s += 256) {
        const bf16x8* row = reinterpret_cast<const bf16x8*>(kp + (size_t)s * HEAD_DIM);
        float ss = 0.f;
        #pragma unroll
        for (int j = 0; j < 8; ++j) {
            bf16x8 v = row[j];
            #pragma unroll
            for (int e = 0; e < 8; ++e) {
                float f = bf2f((u16)v[e]);
                ss = fmaf(f, f, ss);
            }
        }
        mx = fmaxf(mx, ss);
    }
    red[threadIdx.x] = mx;
    __syncthreads();
    for (int off = 128; off; off >>= 1) {
        if (threadIdx.x < (unsigned)off)
            red[threadIdx.x] = fmaxf(red[threadIdx.x], red[threadIdx.x + off]);
        __syncthreads();
    }
    if (threadIdx.x == 0) kn[bh] = sqrtf(red[0]);
}

// ---------------- Flash attention: persistent split-K + K/V register prefetch ----------------
__global__ __launch_bounds__(256) void attn(
        const u16* __restrict__ Q, const u16* __restrict__ Kb,
        const u16* __restrict__ VT, const float* __restrict__ alibi,
        const float* __restrict__ kn, u16* __restrict__ ctx,
        unsigned int* __restrict__ ctr) {
    __shared__ float o_l[4][64][33];
    __shared__ float ml[4][2][32];
    __shared__ unsigned int s_idx;
    const int wave = threadIdx.x >> 6;
    const int lane = threadIdx.x & 63;
    const int la = lane & 31, hi = lane >> 5;

    for (;;) {
        if (threadIdx.x == 0) s_idx = atomicAdd(ctr, 1u);
        __syncthreads();                     // publish s_idx; protect o_l reuse
        const unsigned int idx = s_idx;
        if (idx >= N_ITEMS) return;
        const int bh = idx & 31;
        const int qt = 63 - (int)(idx >> 5); // heavy q-tiles first
        const int qw = qt * 32;
        const size_t sb = (size_t)bh * SEQ;
        const float slope2 = alibi[sb + 1] * LOG2E;

        const u16* qp = Q + (sb + qw + la) * HEAD_DIM + hi * 8;
        bf16x8 qf0 = *reinterpret_cast<const bf16x8*>(qp);
        bf16x8 qf1 = *reinterpret_cast<const bf16x8*>(qp + 16);
        bf16x8 qf2 = *reinterpret_cast<const bf16x8*>(qp + 32);
        bf16x8 qf3 = *reinterpret_cast<const bf16x8*>(qp + 48);

        f32x16 o0 = {}, o1 = {};
        float m_i = -INFINITY, l_i = 0.f;

        int t = qt - wave;
        if (t >= 0) {
            float qss = 0.f;
            #pragma unroll
            for (int e = 0; e < 8; ++e) {
                float f;
                f = bf2f((u16)qf0[e]); qss = fmaf(f, f, qss);
                f = bf2f((u16)qf1[e]); qss = fmaf(f, f, qss);
                f = bf2f((u16)qf2[e]); qss = fmaf(f, f, qss);
                f = bf2f((u16)qf3[e]); qss = fmaf(f, f, qss);
            }
            qss += __shfl_xor(qss, 32);
            float qmx = qss;
            #pragma unroll
            for (int off = 1; off <= 16; off <<= 1) qmx = fmaxf(qmx, __shfl_xor(qmx, off));
            const float kb = sqrtf(qmx) * kn[bh] * IN2;

            float skr2[16];
            #pragma unroll
            for (int r = 0; r < 16; ++r)
                skr2[r] = slope2 * (float)((r & 3) + 8 * (r >> 2) + 4 * hi);

            // prologue: load tile t
            const u16* kp = Kb + (sb + t * 32 + la) * HEAD_DIM + hi * 8;
            bf16x8 kc0 = *reinterpret_cast<const bf16x8*>(kp);
            bf16x8 kc1 = *reinterpret_cast<const bf16x8*>(kp + 16);
            bf16x8 kc2 = *reinterpret_cast<const bf16x8*>(kp + 32);
            bf16x8 kc3 = *reinterpret_cast<const bf16x8*>(kp + 48);
            const u16* vp = VT + ((size_t)bh * HEAD_DIM + la) * SEQ + t * 32 + hi * 8;
            bf16x8 vc00 = *reinterpret_cast<const bf16x8*>(vp);
            bf16x8 vc01 = *reinterpret_cast<const bf16x8*>(vp + 16);
            bf16x8 vc10 = *reinterpret_cast<const bf16x8*>(vp + 32 * SEQ);
            bf16x8 vc11 = *reinterpret_cast<const bf16x8*>(vp + 32 * SEQ + 16);

            for (;;) {
                const int k0 = t * 32;
                f32x16 sca = {}, scb = {};
                sca = mfma32(kc0, qf0, sca);
                scb = mfma32(kc1, qf1, scb);
                sca = mfma32(kc2, qf2, sca);
                scb = mfma32(kc3, qf3, scb);

                // prefetch tile t-4 (clamped): latency hides under softmax+PV
                const int tn = t - 4;
                const int tp = tn >= 0 ? tn : 0;
                const u16* kpn = Kb + (sb + tp * 32 + la) * HEAD_DIM + hi * 8;
                bf16x8 kn0 = *reinterpret_cast<const bf16x8*>(kpn);
                bf16x8 kn1 = *reinterpret_cast<const bf16x8*>(kpn + 16);
                bf16x8 kn2 = *reinterpret_cast<const bf16x8*>(kpn + 32);
                bf16x8 kn3 = *reinterpret_cast<const bf16x8*>(kpn + 48);
                const u16* vpn = VT + ((size_t)bh * HEAD_DIM + la) * SEQ + tp * 32 + hi * 8;
                bf16x8 vn00 = *reinterpret_cast<const bf16x8*>(vpn);
                bf16x8 vn01 = *reinterpret_cast<const bf16x8*>(vpn + 16);
                bf16x8 vn10 = *reinterpret_cast<const bf16x8*>(vpn + 32 * SEQ);
                bf16x8 vn11 = *reinterpret_cast<const bf16x8*>(vpn + 32 * SEQ + 16);

                float s[16];
                const float base2 = slope2 * (float)k0;
                #pragma unroll
                for (int r = 0; r < 16; ++r)
                    s[r] = fmaf(sca[r] + scb[r], IN2, base2 + skr2[r]);
                if (t == qt) {   // diagonal tile (wave 0 only)
                    #pragma unroll
                    for (int r = 0; r < 16; ++r) {
                        int kr = (r & 3) + 8 * (r >> 2) + 4 * hi;
                        if (kr > la) s[r] = -INFINITY;
                    }
                }
                float ma = fmaxf(fmaxf(s[0], s[1]), fmaxf(s[2], s[3]));
                float mb = fmaxf(fmaxf(s[4], s[5]), fmaxf(s[6], s[7]));
                float mc = fmaxf(fmaxf(s[8], s[9]), fmaxf(s[10], s[11]));
                float md = fmaxf(fmaxf(s[12], s[13]), fmaxf(s[14], s[15]));
                float mx = fmaxf(fmaxf(ma, mb), fmaxf(mc, md));
                mx = fmaxf(mx, __shfl_xor(mx, 32));
                if (!__all(mx <= m_i + 11.54f)) {   // defer-max (T13)
                    float mnew = fmaxf(m_i, mx);
                    float scl = fexp2(m_i - mnew);
                    l_i *= scl;
                    #pragma unroll
                    for (int r = 0; r < 16; ++r) { o0[r] *= scl; o1[r] *= scl; }
                    m_i = mnew;
                }
                #pragma unroll
                for (int r = 0; r < 16; ++r) s[r] = fexp2(s[r] - m_i);
                float sa = (s[0] + s[1]) + (s[2] + s[3]);
                float sbs = (s[4] + s[5]) + (s[6] + s[7]);
                float scs = (s[8] + s[9]) + (s[10] + s[11]);
                float sd = (s[12] + s[13]) + (s[14] + s[15]);
                float rs = (sa + sbs) + (scs + sd);
                rs += __shfl_xor(rs, 32);
                l_i += rs;

                unsigned int pk[8], swp[8];
                #pragma unroll
                for (int m = 0; m < 4; ++m) {
                    pk[2 * m]     = (unsigned)f2bf(s[4 * m])     | ((unsigned)f2bf(s[4 * m + 1]) << 16);
                    pk[2 * m + 1] = (unsigned)f2bf(s[4 * m + 2]) | ((unsigned)f2bf(s[4 * m + 3]) << 16);
                }
                #pragma unroll
                for (int i = 0; i < 8; ++i) swp[i] = __shfl_xor(pk[i], 32);
                u32x4 pb0, pb1;
                pb0[0] = hi ? swp[2] : pk[0];  pb0[1] = hi ? swp[3] : pk[1];
                pb0[2] = hi ? pk[2]  : swp[0]; pb0[3] = hi ? pk[3]  : swp[1];
                pb1[0] = hi ? swp[6] : pk[4];  pb1[1] = hi ? swp[7] : pk[5];
                pb1[2] = hi ? pk[6]  : swp[4]; pb1[3] = hi ? pk[7]  : swp[5];
                bf16x8 pf0 = __builtin_bit_cast(bf16x8, pb0);
                bf16x8 pf1 = __builtin_bit_cast(bf16x8, pb1);

                o0 = mfma32(vc00, pf0, o0);
                o0 = mfma32(vc01, pf1, o0);
                o1 = mfma32(vc10, pf0, o1);
                o1 = mfma32(vc11, pf1, o1);

                kc0 = kn0; kc1 = kn1; kc2 = kn2; kc3 = kn3;
                vc00 = vn00; vc01 = vn01; vc10 = vn10; vc11 = vn11;
                t = tn;
                if (t < 0) break;
                if (__all(kb + slope2 * (float)(k0 - 128 + 31) < m_i - 36.f)) break;
            }
        }

        // ---- write partials to LDS ----
        if (hi == 0) { ml[wave][0][la] = m_i; ml[wave][1][la] = l_i; }
        #pragma unroll
        for (int r = 0; r < 16; ++r) {
            int d = (r & 3) + 8 * (r >> 2) + 4 * hi;
            o_l[wave][d][la]      = o0[r];
            o_l[wave][d + 32][la] = o1[r];
        }
        __syncthreads();

        // ---- combine: thread = (q, 8-wide d slab) ----
        const int q  = threadIdx.x >> 3;
        const int d0 = (threadIdx.x & 7) * 8;
        float m0w = ml[0][0][q], m1w = ml[1][0][q], m2w = ml[2][0][q], m3w = ml[3][0][q];
        float M = fmaxf(fmaxf(m0w, m1w), fmaxf(m2w, m3w));
        float s0 = fexp2(m0w - M), s1 = fexp2(m1w - M);
        float s2 = fexp2(m2w - M), s3 = fexp2(m3w - M);
        float L = s0 * ml[0][1][q] + s1 * ml[1][1][q] + s2 * ml[2][1][q] + s3 * ml[3][1][q];
        float inv = 1.0f / L;
        unsigned int packed[4];
        #pragma unroll
        for (int e2 = 0; e2 < 4; ++e2) {
            float Oa = s0 * o_l[0][d0 + 2 * e2][q] + s1 * o_l[1][d0 + 2 * e2][q]
                     + s2 * o_l[2][d0 + 2 * e2][q] + s3 * o_l[3][d0 + 2 * e2][q];
            float Ob = s0 * o_l[0][d0 + 2 * e2 + 1][q] + s1 * o_l[1][d0 + 2 * e2 + 1][q]
                     + s2 * o_l[2][d0 + 2 * e2 + 1][q] + s3 * o_l[3][d0 + 2 * e2 + 1][q];
            packed[e2] = (unsigned)f2bf(Oa * inv) | ((unsigned)f2bf(Ob * inv) << 16);
        }
        const int b = bh >> 4, h = bh & 15;
        u32x4 pv; pv[0] = packed[0]; pv[1] = packed[1]; pv[2] = packed[2]; pv[3] = packed[3];
        *reinterpret_cast<u32x4*>(
            &ctx[((size_t)(b * SEQ + qw + q)) * HIDDEN + h * HEAD_DIM + d0]) = pv;
    }
}

extern "C" void kernel_launch(void* const* d_in, const int* in_sizes, int n_in,
                              void* d_out, int out_size, void* d_ws, size_t ws_size,
                              hipStream_t stream) {
    const float* x        = (const float*)d_in[0];
    const float* residual = (const float*)d_in[1];
    const float* alibi    = (const float*)d_in[2];
    const float* W_qkv    = (const float*)d_in[4];
    const float* b_qkv    = (const float*)d_in[5];
    const float* W_dense  = (const float*)d_in[6];
    const float* b_dense  = (const float*)d_in[7];
    float* out = (float*)d_out;

    char* ws = (char*)d_ws;
    u16* xb  = (u16*)(ws);                 //  8 MB  x bf16
    u16* wqb = (u16*)(ws + 8388608);       //  6 MB  W_qkv bf16
    u16* wdb = (u16*)(ws + 14680064);      //  2 MB  W_dense bf16
    u16* q   = (u16*)(ws + 16777216);      //  8 MB  [B][H][S][64]
    u16* k   = (u16*)(ws + 25165824);      //  8 MB  [B][H][S][64]
    u16* vT  = (u16*)(ws + 33554432);      //  8 MB  [B][H][64][S]
    u16* ctx = (u16*)(ws + 41943040);      //  8 MB  [B*S][1024]
    float* kn = (float*)(ws + 50331648);   //  128 B per-bh max ||k||
    unsigned int* ctr = (unsigned int*)(ws + 50331648 + 256);

    cvt_all<<<8192, 256, 0, stream>>>(x, W_qkv, W_dense, xb, wqb, wdb);
    gemm_qkv<<<768, 256, 0, stream>>>(xb, wqb, b_qkv, q, k, vT);
    knorm_max<<<32, 256, 0, stream>>>(k, kn, ctr);
    attn<<<1024, 256, 0, stream>>>(q, k, vT, alibi, kn, ctx, ctr);
    gemm_dense<<<256, 256, 0, stream>>>(ctx, wdb, b_dense, residual, out);
}